// Round 1
// baseline (508.151 us; speedup 1.0000x reference)
//
#include <hip/hip_runtime.h>
#include <hip/hip_fp16.h>
#include <math.h>

#define N_NODES 50000
#define N_EDGES 800000
#define DIM 128
#define NHEADS 8
#define LN_EPS 1e-5f
#define LEAKY 0.2f
#define NSB 196    // ceil(N_NODES/256) scan blocks
#define NBINS 512
#define NPB 98     // nodes per bin; 512*98 = 50176 >= N_NODES

typedef _Float16 half8 __attribute__((ext_vector_type(8)));
typedef float floatx4 __attribute__((ext_vector_type(4)));

// ---------------- pack/unpack (P, deter) as half2 in one int ----------------
__device__ __forceinline__ int pack_pd(float p, float dt) {
    __half2 h = __floats2half2_rn(p, dt);
    int r; __builtin_memcpy(&r, &h, 4); return r;
}
__device__ __forceinline__ float2 unpack_pd(int v) {
    __half2 h; __builtin_memcpy(&h, &v, 4);
    return __half22float2(h);   // .x = P, .y = deter
}

// ------ K1: Wcat rows 128..135 = fp16(W4@W1), 136..143 = fp16(W4@W2); c -----
__global__ __launch_bounds__(128) void k_prep(
    const float* __restrict__ W1, const float* __restrict__ W2,
    const float* __restrict__ W3, const float* __restrict__ W4,
    __half* __restrict__ Wcat, float* __restrict__ c) {
    int h = blockIdx.x;       // 0..7
    int k = threadIdx.x;      // 0..127
    float a1 = 0.f, a2 = 0.f;
    for (int d = 0; d < DIM; ++d) {
        float w4 = W4[h * DIM + d];
        a1 += w4 * W1[d * DIM + k];
        a2 += w4 * W2[d * DIM + k];
    }
    Wcat[(size_t)(128 + h) * DIM + k] = __float2half_rn(a1);
    Wcat[(size_t)(136 + h) * DIM + k] = __float2half_rn(a2);
    __shared__ float red[DIM];
    red[k] = W4[h * DIM + k] * W3[k];
    __syncthreads();
    if (k == 0) {
        float s = 0.f;
        for (int i = 0; i < DIM; ++i) s += red[i];
        c[h] = s;
    }
}

// -- K1b: Wch = fp16[Wout|res_w] (128x256); Wcat rows 0..127 = fp16(Wv); bsum
__global__ __launch_bounds__(256) void k_wcat(
    const float* __restrict__ Wout, const float* __restrict__ Wres,
    const float* __restrict__ Wv, const float* __restrict__ bout,
    const float* __restrict__ bres, __half* __restrict__ Wch,
    __half* __restrict__ Wcat, float* __restrict__ bsum) {
    int d = blockIdx.x;     // 0..127
    int t = threadIdx.x;    // 0..255
    float v = (t < 128) ? Wout[d * 128 + t] : Wres[d * 128 + (t - 128)];
    Wch[(size_t)d * 256 + t] = __float2half_rn(v);
    if (t < 128) Wcat[(size_t)d * DIM + t] = __float2half_rn(Wv[d * 128 + t]);
    if (d == 0 && t < 128) bsum[t] = bout[t] + bres[t];
}

// -- K2: MFMA  Y = H @ Wcat^T  (M=N_NODES, N=144, K=128, fp16 in / fp32 acc) -
//   cols 0..127 -> Vh (fp16), cols 128..135 -> A1, 136..143 -> A2 (fp32)
//   side effect: Xh[:,128:256] = fp16(H)  (converted A-fragments)
__global__ __launch_bounds__(64) void k_node_mfma(
    const float* __restrict__ H, const __half* __restrict__ Wcat_,
    __half* __restrict__ Vh, __half* __restrict__ Xh,
    float* __restrict__ A1, float* __restrict__ A2) {
    const _Float16* Wcat = reinterpret_cast<const _Float16*>(Wcat_);
    int lane = threadIdx.x;          // 0..63
    int m = lane & 15, q = lane >> 4;
    int n0 = blockIdx.x * 32;
    floatx4 z = {0.f, 0.f, 0.f, 0.f};
    floatx4 acc[2][9];
    #pragma unroll
    for (int t = 0; t < 2; ++t)
        #pragma unroll
        for (int j = 0; j < 9; ++j) acc[t][j] = z;
    int r0 = n0 + m;        if (r0 >= N_NODES) r0 = N_NODES - 1;
    int r1 = n0 + 16 + m;   if (r1 >= N_NODES) r1 = N_NODES - 1;
    const float* H0 = H + (size_t)r0 * DIM + q * 8;
    const float* H1 = H + (size_t)r1 * DIM + q * 8;
    _Float16* Xw0 = reinterpret_cast<_Float16*>(Xh) + (size_t)r0 * 256 + 128 + q * 8;
    _Float16* Xw1 = reinterpret_cast<_Float16*>(Xh) + (size_t)r1 * 256 + 128 + q * 8;
    const _Float16* Wb = Wcat + (size_t)m * DIM + q * 8;
    #pragma unroll
    for (int ks = 0; ks < 4; ++ks) {
        float4 fa = *reinterpret_cast<const float4*>(H0 + ks * 32);
        float4 fb = *reinterpret_cast<const float4*>(H0 + ks * 32 + 4);
        float4 ga = *reinterpret_cast<const float4*>(H1 + ks * 32);
        float4 gb = *reinterpret_cast<const float4*>(H1 + ks * 32 + 4);
        half8 a0, a1v;
        a0[0] = (_Float16)fa.x; a0[1] = (_Float16)fa.y;
        a0[2] = (_Float16)fa.z; a0[3] = (_Float16)fa.w;
        a0[4] = (_Float16)fb.x; a0[5] = (_Float16)fb.y;
        a0[6] = (_Float16)fb.z; a0[7] = (_Float16)fb.w;
        a1v[0] = (_Float16)ga.x; a1v[1] = (_Float16)ga.y;
        a1v[2] = (_Float16)ga.z; a1v[3] = (_Float16)ga.w;
        a1v[4] = (_Float16)gb.x; a1v[5] = (_Float16)gb.y;
        a1v[6] = (_Float16)gb.z; a1v[7] = (_Float16)gb.w;
        *reinterpret_cast<half8*>(Xw0 + ks * 32) = a0;
        *reinterpret_cast<half8*>(Xw1 + ks * 32) = a1v;
        #pragma unroll
        for (int j = 0; j < 9; ++j) {
            half8 b = *reinterpret_cast<const half8*>(Wb + (size_t)j * 16 * DIM + ks * 32);
            acc[0][j] = __builtin_amdgcn_mfma_f32_16x16x32_f16(a0, b, acc[0][j], 0, 0, 0);
            acc[1][j] = __builtin_amdgcn_mfma_f32_16x16x32_f16(a1v, b, acc[1][j], 0, 0, 0);
        }
    }
    // C/D layout: col = m, row = q*4 + reg (within 16-row tile)
    #pragma unroll
    for (int t = 0; t < 2; ++t) {
        #pragma unroll
        for (int reg = 0; reg < 4; ++reg) {
            int n = n0 + t * 16 + q * 4 + reg;
            if (n < N_NODES) {
                #pragma unroll
                for (int j = 0; j < 8; ++j)
                    Vh[(size_t)n * DIM + j * 16 + m] = __float2half_rn(acc[t][j][reg]);
                float av = acc[t][8][reg];
                if (m < 8) A1[(size_t)n * NHEADS + m] = av;
                else       A2[(size_t)n * NHEADS + (m - 8)] = av;
            }
        }
    }
}

// ---------------- K3: degree histogram --------------------------------------
__global__ __launch_bounds__(256) void k_hist(
    const int* __restrict__ ei, int* __restrict__ deg) {
    int e = blockIdx.x * 256 + threadIdx.x;
    if (e < N_EDGES) atomicAdd(&deg[ei[N_EDGES + e]], 1);
}

// ---------------- K4a: per-block partial sums of deg ------------------------
__global__ __launch_bounds__(256) void k_scan1(
    const int* __restrict__ deg, int* __restrict__ partial) {
    int t = threadIdx.x;
    int idx = blockIdx.x * 256 + t;
    int v = (idx < N_NODES) ? deg[idx] : 0;
    #pragma unroll
    for (int off = 32; off > 0; off >>= 1) v += __shfl_down(v, off, 64);
    __shared__ int ws_[4];
    if ((t & 63) == 0) ws_[t >> 6] = v;
    __syncthreads();
    if (t == 0) partial[blockIdx.x] = ws_[0] + ws_[1] + ws_[2] + ws_[3];
}

// -------- K4b: per-block local scan; each block also scans the partials -----
__global__ __launch_bounds__(256) void k_scan3(
    const int* __restrict__ deg, const int* __restrict__ partial,
    int* __restrict__ row_off, int* __restrict__ cursor) {
    __shared__ int shp[256];
    __shared__ int sh[256];
    int t = threadIdx.x;
    int pv = (t < NSB) ? partial[t] : 0;
    shp[t] = pv;
    int idx = blockIdx.x * 256 + t;
    int v = (idx < N_NODES) ? deg[idx] : 0;
    sh[t] = v;
    __syncthreads();
    #pragma unroll
    for (int off = 1; off < 256; off <<= 1) {
        int u1 = (t >= off) ? shp[t - off] : 0;
        int u2 = (t >= off) ? sh[t - off] : 0;
        __syncthreads();
        shp[t] += u1;
        sh[t] += u2;
        __syncthreads();
    }
    int pofs = (blockIdx.x == 0) ? 0 : shp[blockIdx.x - 1];
    int excl = sh[t] - v + pofs;
    if (idx < N_NODES) {
        row_off[idx] = excl;
        cursor[idx] = excl;
    }
    if (idx == N_NODES - 1) row_off[N_NODES] = excl + v;   // == N_EDGES
}

// ---------------- K4c: bin cursors = row_off at bin boundaries --------------
__global__ __launch_bounds__(256) void k_bininit(
    const int* __restrict__ row_off, int* __restrict__ binCur) {
    int b = blockIdx.x * 256 + threadIdx.x;
    if (b < NBINS) {
        int node = b * NPB;
        if (node > N_NODES) node = N_NODES;
        binCur[b] = row_off[node];
    }
}

// ---------------- K5a: coarse binned scatter (phase 1) ----------------------
// record = ((dst<<16)|src, half2(P,deter)); appended to bin region dst/NPB.
// Appends to 512 hot regions -> dense increasing addresses -> lines fill
// fully in L2 before writeback (~1x write amplification vs 8x random).
__global__ __launch_bounds__(256) void k_bin(
    const int* __restrict__ ei, const float* __restrict__ P,
    const float* __restrict__ deter, int* __restrict__ binCur,
    int2* __restrict__ rec_tmp) {
    int e = blockIdx.x * 256 + threadIdx.x;
    if (e >= N_EDGES) return;
    int src = ei[e];
    int dst = ei[N_EDGES + e];
    int bin = dst / NPB;
    int pos = atomicAdd(&binCur[bin], 1);
    rec_tmp[pos] = make_int2((dst << 16) | src, pack_pd(P[e], deter[e]));
}

// ---------------- K5b: exact scatter within bin (phase 2) -------------------
// One block per bin. Source range and dest range are the SAME ~12-25 KB
// window [row_off[bin*NPB], row_off[(bin+1)*NPB]) -> L2-resident scatter.
__global__ __launch_bounds__(256) void k_rebin(
    const int* __restrict__ row_off, const int2* __restrict__ rec_tmp,
    int* __restrict__ cursor, int2* __restrict__ rec) {
    int bin = blockIdx.x;
    int n0 = bin * NPB;       if (n0 > N_NODES) n0 = N_NODES;
    int n1 = n0 + NPB;        if (n1 > N_NODES) n1 = N_NODES;
    int s = row_off[n0];
    int e = row_off[n1];
    for (int i = s + threadIdx.x; i < e; i += 256) {
        int2 r = rec_tmp[i];
        int dst = ((unsigned)r.x) >> 16;
        int src = r.x & 0xFFFF;
        int pos = atomicAdd(&cursor[dst], 1);
        rec[pos] = make_int2(src, r.y);
    }
}

// ---------------- K6: fused softmax + aggregation (4x unrolled) -------------
// wave per node; lane d owns dims (2d, 2d+1) -> head h = d>>3
// writes fp16 result into Xh[n][0:128]
__global__ __launch_bounds__(256) void k_sm_agg(
    const int* __restrict__ row_off, const int2* __restrict__ rec,
    const float* __restrict__ A1, const float* __restrict__ A2,
    const float* __restrict__ cvec, const __half2* __restrict__ Vh2,
    __half* __restrict__ Xh) {
    int n = (blockIdx.x * 256 + threadIdx.x) >> 6;
    int d = threadIdx.x & 63;
    if (n >= N_NODES) return;
    int h = d >> 3;
    float a1 = A1[(size_t)n * NHEADS + h];
    float ch = cvec[h];
    int start = row_off[n], end = row_off[n + 1];
    float s = 0.f, accx = 0.f, accy = 0.f;
    int j = start;
    for (; j + 4 <= end; j += 4) {
        int2 r0 = rec[j], r1 = rec[j + 1], r2 = rec[j + 2], r3 = rec[j + 3];
        int s0 = r0.x, s1 = r1.x, s2 = r2.x, s3 = r3.x;
        float a20 = A2[(size_t)s0 * NHEADS + h];
        float a21 = A2[(size_t)s1 * NHEADS + h];
        float a22 = A2[(size_t)s2 * NHEADS + h];
        float a23 = A2[(size_t)s3 * NHEADS + h];
        __half2 v0 = Vh2[(size_t)s0 * (DIM / 2) + d];
        __half2 v1 = Vh2[(size_t)s1 * (DIM / 2) + d];
        __half2 v2 = Vh2[(size_t)s2 * (DIM / 2) + d];
        __half2 v3 = Vh2[(size_t)s3 * (DIM / 2) + d];
        float2 p0 = unpack_pd(r0.y), p1 = unpack_pd(r1.y);
        float2 p2 = unpack_pd(r2.y), p3 = unpack_pd(r3.y);
        float l0 = a1 + a20 + p0.x * ch + p0.y;
        float l1 = a1 + a21 + p1.x * ch + p1.y;
        float l2 = a1 + a22 + p2.x * ch + p2.y;
        float l3 = a1 + a23 + p3.x * ch + p3.y;
        l0 = (l0 >= 0.f) ? l0 : LEAKY * l0;
        l1 = (l1 >= 0.f) ? l1 : LEAKY * l1;
        l2 = (l2 >= 0.f) ? l2 : LEAKY * l2;
        l3 = (l3 >= 0.f) ? l3 : LEAKY * l3;
        float e0 = __expf(l0), e1 = __expf(l1), e2 = __expf(l2), e3 = __expf(l3);
        s += e0 + e1 + e2 + e3;
        float2 f0 = __half22float2(v0), f1 = __half22float2(v1);
        float2 f2 = __half22float2(v2), f3 = __half22float2(v3);
        accx += e0 * f0.x + e1 * f1.x + e2 * f2.x + e3 * f3.x;
        accy += e0 * f0.y + e1 * f1.y + e2 * f2.y + e3 * f3.y;
    }
    for (; j < end; ++j) {
        int2 r = rec[j];
        int src = r.x;
        float2 pd = unpack_pd(r.y);
        float l = a1 + A2[(size_t)src * NHEADS + h] + pd.x * ch + pd.y;
        l = (l >= 0.f) ? l : LEAKY * l;
        float ex = __expf(l);
        s += ex;
        float2 vf = __half22float2(Vh2[(size_t)src * (DIM / 2) + d]);
        accx += ex * vf.x;
        accy += ex * vf.y;
    }
    float inv = 1.f / (s + 1e-12f);
    __half2 o = __floats2half2_rn(accx * inv, accy * inv);
    *reinterpret_cast<__half2*>(Xh + (size_t)n * 256 + 2 * d) = o;
}

// -- K7: out = Xh(N,256) @ Wch(128,256)^T + bsum, LayerNorm — MFMA -----------
__global__ __launch_bounds__(64) void k_out_mfma(
    const __half* __restrict__ Xh_, const __half* __restrict__ Wch_,
    const float* __restrict__ bsum, const float* __restrict__ ln_g,
    const float* __restrict__ ln_b, float* __restrict__ out) {
    const _Float16* Xh = reinterpret_cast<const _Float16*>(Xh_);
    const _Float16* Wch = reinterpret_cast<const _Float16*>(Wch_);
    int lane = threadIdx.x;          // 0..63
    int m = lane & 15, q = lane >> 4;
    int n0 = blockIdx.x * 32;
    floatx4 z = {0.f, 0.f, 0.f, 0.f};
    floatx4 acc[2][8];
    #pragma unroll
    for (int t = 0; t < 2; ++t)
        #pragma unroll
        for (int j = 0; j < 8; ++j) acc[t][j] = z;
    int r0 = n0 + m;        if (r0 >= N_NODES) r0 = N_NODES - 1;
    int r1 = n0 + 16 + m;   if (r1 >= N_NODES) r1 = N_NODES - 1;
    const _Float16* X0 = Xh + (size_t)r0 * 256 + q * 8;
    const _Float16* X1 = Xh + (size_t)r1 * 256 + q * 8;
    const _Float16* Wb = Wch + (size_t)m * 256 + q * 8;
    #pragma unroll
    for (int ks = 0; ks < 8; ++ks) {
        half8 a0 = *reinterpret_cast<const half8*>(X0 + ks * 32);
        half8 a1 = *reinterpret_cast<const half8*>(X1 + ks * 32);
        #pragma unroll
        for (int j = 0; j < 8; ++j) {
            half8 b = *reinterpret_cast<const half8*>(Wb + (size_t)j * 16 * 256 + ks * 32);
            acc[0][j] = __builtin_amdgcn_mfma_f32_16x16x32_f16(a0, b, acc[0][j], 0, 0, 0);
            acc[1][j] = __builtin_amdgcn_mfma_f32_16x16x32_f16(a1, b, acc[1][j], 0, 0, 0);
        }
    }
    float bsv[8], gv[8], bv[8];
    #pragma unroll
    for (int j = 0; j < 8; ++j) {
        bsv[j] = bsum[j * 16 + m];
        gv[j]  = ln_g[j * 16 + m];
        bv[j]  = ln_b[j * 16 + m];
    }
    #pragma unroll
    for (int t = 0; t < 2; ++t) {
        #pragma unroll
        for (int reg = 0; reg < 4; ++reg) {
            float v[8];
            float s = 0.f, sq = 0.f;
            #pragma unroll
            for (int j = 0; j < 8; ++j) {
                v[j] = acc[t][j][reg] + bsv[j];
                s += v[j];
                sq += v[j] * v[j];
            }
            #pragma unroll
            for (int mk = 1; mk < 16; mk <<= 1) {
                s  += __shfl_xor(s, mk, 64);
                sq += __shfl_xor(sq, mk, 64);
            }
            float mu = s * (1.f / DIM);
            float var = sq * (1.f / DIM) - mu * mu;
            float rs = rsqrtf(var + LN_EPS);
            int n = n0 + t * 16 + q * 4 + reg;
            if (n < N_NODES) {
                #pragma unroll
                for (int j = 0; j < 8; ++j)
                    out[(size_t)n * DIM + j * 16 + m] = (v[j] - mu) * rs * gv[j] + bv[j];
            }
        }
    }
}

// ---------------------------------------------------------------------------
extern "C" void kernel_launch(void* const* d_in, const int* in_sizes, int n_in,
                              void* d_out, int out_size, void* d_ws, size_t ws_size,
                              hipStream_t stream) {
    const float* H      = (const float*)d_in[0];
    const int*   ei     = (const int*)d_in[1];
    const float* P      = (const float*)d_in[2];
    const float* deter  = (const float*)d_in[3];
    const float* W1     = (const float*)d_in[4];
    const float* W2     = (const float*)d_in[5];
    const float* W3     = (const float*)d_in[6];
    const float* W4     = (const float*)d_in[7];
    const float* Wv     = (const float*)d_in[8];
    const float* Wout_w = (const float*)d_in[9];
    const float* Wout_b = (const float*)d_in[10];
    const float* res_w  = (const float*)d_in[11];
    const float* res_b  = (const float*)d_in[12];
    const float* ln_g   = (const float*)d_in[13];
    const float* ln_b   = (const float*)d_in[14];

    float* ws = (float*)d_ws;
    const size_t NH8 = (size_t)N_NODES * NHEADS;   // 400,000

    __half* Xh  = (__half*)ws;                       // N*256 halves = N*128 words
    float* fbase = ws + (size_t)N_NODES * 128;
    __half* Vh  = (__half*)fbase;                    // N*128 halves = N*64 words
    float* A1   = fbase + (size_t)N_NODES * 64;      // NH8
    float* A2   = A1 + NH8;                          // NH8
    float* cvec = A2 + NH8;                          // 16
    float* bsum = cvec + 16;                         // 128
    __half* Wch  = (__half*)(bsum + 128);            // 128*256 halves = 16384 words
    __half* Wcat = Wch + 128 * 256;                  // 144*128 halves = 9216 words
    int2*  rec  = (int2*)(Wcat + 144 * 128);         // E records (8B each)
    int* deg     = (int*)(rec + N_EDGES);            // N
    int* row_off = deg + N_NODES;                    // N+1
    int* cursor  = row_off + N_NODES + 1;            // N
    int* partial = cursor + N_NODES;                 // 256
    int* binCur  = partial + 256;                    // NBINS
    // total ~12.2M words (~49 MB)

    // phase-1 staging buffer lives in d_out (6.4 MB << 25.6 MB; d_out is
    // fully overwritten by k_out_mfma at the end)
    int2* rec_tmp = (int2*)d_out;

    hipMemsetAsync(deg, 0, N_NODES * sizeof(int), stream);

    k_prep<<<NHEADS, DIM, 0, stream>>>(W1, W2, W3, W4, Wcat, cvec);
    k_wcat<<<DIM, 256, 0, stream>>>(Wout_w, res_w, Wv, Wout_b, res_b, Wch, Wcat, bsum);
    k_node_mfma<<<(N_NODES + 31) / 32, 64, 0, stream>>>(H, Wcat, Vh, Xh, A1, A2);
    k_hist<<<(N_EDGES + 255) / 256, 256, 0, stream>>>(ei, deg);
    k_scan1<<<NSB, 256, 0, stream>>>(deg, partial);
    k_scan3<<<NSB, 256, 0, stream>>>(deg, partial, row_off, cursor);
    k_bininit<<<(NBINS + 255) / 256, 256, 0, stream>>>(row_off, binCur);
    k_bin<<<(N_EDGES + 255) / 256, 256, 0, stream>>>(ei, P, deter, binCur, rec_tmp);
    k_rebin<<<NBINS, 256, 0, stream>>>(row_off, rec_tmp, cursor, rec);
    k_sm_agg<<<(N_NODES + 3) / 4, 256, 0, stream>>>(row_off, rec, A1, A2, cvec,
                                                    (const __half2*)Vh, Xh);
    k_out_mfma<<<(N_NODES + 31) / 32, 64, 0, stream>>>(Xh, Wch, bsum, ln_g, ln_b,
                                                       (float*)d_out);
}

// Round 3
// 293.994 us; speedup vs baseline: 1.7284x; 1.7284x over previous
//
#include <hip/hip_runtime.h>
#include <hip/hip_fp16.h>
#include <math.h>

#define N_NODES 50000
#define N_EDGES 800000
#define DIM 128
#define NHEADS 8
#define LN_EPS 1e-5f
#define LEAKY 0.2f
#define NSB 196    // ceil(N_NODES/256) scan blocks
#define NBINS 512
#define NPB 98     // nodes per bin; 512*98 = 50176 >= N_NODES
#define NCHUNK 128 // edge chunks for counting sort
#define EPC 6250   // edges per chunk; 128*6250 = 800000 exactly

typedef _Float16 half8 __attribute__((ext_vector_type(8)));
typedef float floatx4 __attribute__((ext_vector_type(4)));

// ---------------- pack/unpack (P, deter) as half2 in one int ----------------
__device__ __forceinline__ int pack_pd(float p, float dt) {
    __half2 h = __floats2half2_rn(p, dt);
    int r; __builtin_memcpy(&r, &h, 4); return r;
}
__device__ __forceinline__ float2 unpack_pd(int v) {
    __half2 h; __builtin_memcpy(&h, &v, 4);
    return __half22float2(h);   // .x = P, .y = deter
}

// ------ K1: Wcat rows 128..135 = fp16(W4@W1), 136..143 = fp16(W4@W2); c -----
__global__ __launch_bounds__(128) void k_prep(
    const float* __restrict__ W1, const float* __restrict__ W2,
    const float* __restrict__ W3, const float* __restrict__ W4,
    __half* __restrict__ Wcat, float* __restrict__ c) {
    int h = blockIdx.x;       // 0..7
    int k = threadIdx.x;      // 0..127
    float a1 = 0.f, a2 = 0.f;
    for (int d = 0; d < DIM; ++d) {
        float w4 = W4[h * DIM + d];
        a1 += w4 * W1[d * DIM + k];
        a2 += w4 * W2[d * DIM + k];
    }
    Wcat[(size_t)(128 + h) * DIM + k] = __float2half_rn(a1);
    Wcat[(size_t)(136 + h) * DIM + k] = __float2half_rn(a2);
    __shared__ float red[DIM];
    red[k] = W4[h * DIM + k] * W3[k];
    __syncthreads();
    if (k == 0) {
        float s = 0.f;
        for (int i = 0; i < DIM; ++i) s += red[i];
        c[h] = s;
    }
}

// -- K1b: Wch = fp16[Wout|res_w] (128x256); Wcat rows 0..127 = fp16(Wv); bsum
__global__ __launch_bounds__(256) void k_wcat(
    const float* __restrict__ Wout, const float* __restrict__ Wres,
    const float* __restrict__ Wv, const float* __restrict__ bout,
    const float* __restrict__ bres, __half* __restrict__ Wch,
    __half* __restrict__ Wcat, float* __restrict__ bsum) {
    int d = blockIdx.x;     // 0..127
    int t = threadIdx.x;    // 0..255
    float v = (t < 128) ? Wout[d * 128 + t] : Wres[d * 128 + (t - 128)];
    Wch[(size_t)d * 256 + t] = __float2half_rn(v);
    if (t < 128) Wcat[(size_t)d * DIM + t] = __float2half_rn(Wv[d * 128 + t]);
    if (d == 0 && t < 128) bsum[t] = bout[t] + bres[t];
}

// -- K2: MFMA  Y = H @ Wcat^T  (M=N_NODES, N=144, K=128, fp16 in / fp32 acc) -
//   cols 0..127 -> Vh (fp16), cols 128..135 -> A1, 136..143 -> A2 (fp32)
//   side effect: Xh[:,128:256] = fp16(H)  (converted A-fragments)
__global__ __launch_bounds__(64) void k_node_mfma(
    const float* __restrict__ H, const __half* __restrict__ Wcat_,
    __half* __restrict__ Vh, __half* __restrict__ Xh,
    float* __restrict__ A1, float* __restrict__ A2) {
    const _Float16* Wcat = reinterpret_cast<const _Float16*>(Wcat_);
    int lane = threadIdx.x;          // 0..63
    int m = lane & 15, q = lane >> 4;
    int n0 = blockIdx.x * 32;
    floatx4 z = {0.f, 0.f, 0.f, 0.f};
    floatx4 acc[2][9];
    #pragma unroll
    for (int t = 0; t < 2; ++t)
        #pragma unroll
        for (int j = 0; j < 9; ++j) acc[t][j] = z;
    int r0 = n0 + m;        if (r0 >= N_NODES) r0 = N_NODES - 1;
    int r1 = n0 + 16 + m;   if (r1 >= N_NODES) r1 = N_NODES - 1;
    const float* H0 = H + (size_t)r0 * DIM + q * 8;
    const float* H1 = H + (size_t)r1 * DIM + q * 8;
    _Float16* Xw0 = reinterpret_cast<_Float16*>(Xh) + (size_t)r0 * 256 + 128 + q * 8;
    _Float16* Xw1 = reinterpret_cast<_Float16*>(Xh) + (size_t)r1 * 256 + 128 + q * 8;
    const _Float16* Wb = Wcat + (size_t)m * DIM + q * 8;
    #pragma unroll
    for (int ks = 0; ks < 4; ++ks) {
        float4 fa = *reinterpret_cast<const float4*>(H0 + ks * 32);
        float4 fb = *reinterpret_cast<const float4*>(H0 + ks * 32 + 4);
        float4 ga = *reinterpret_cast<const float4*>(H1 + ks * 32);
        float4 gb = *reinterpret_cast<const float4*>(H1 + ks * 32 + 4);
        half8 a0, a1v;
        a0[0] = (_Float16)fa.x; a0[1] = (_Float16)fa.y;
        a0[2] = (_Float16)fa.z; a0[3] = (_Float16)fa.w;
        a0[4] = (_Float16)fb.x; a0[5] = (_Float16)fb.y;
        a0[6] = (_Float16)fb.z; a0[7] = (_Float16)fb.w;
        a1v[0] = (_Float16)ga.x; a1v[1] = (_Float16)ga.y;
        a1v[2] = (_Float16)ga.z; a1v[3] = (_Float16)ga.w;
        a1v[4] = (_Float16)gb.x; a1v[5] = (_Float16)gb.y;
        a1v[6] = (_Float16)gb.z; a1v[7] = (_Float16)gb.w;
        *reinterpret_cast<half8*>(Xw0 + ks * 32) = a0;
        *reinterpret_cast<half8*>(Xw1 + ks * 32) = a1v;
        #pragma unroll
        for (int j = 0; j < 9; ++j) {
            half8 b = *reinterpret_cast<const half8*>(Wb + (size_t)j * 16 * DIM + ks * 32);
            acc[0][j] = __builtin_amdgcn_mfma_f32_16x16x32_f16(a0, b, acc[0][j], 0, 0, 0);
            acc[1][j] = __builtin_amdgcn_mfma_f32_16x16x32_f16(a1v, b, acc[1][j], 0, 0, 0);
        }
    }
    // C/D layout: col = m, row = q*4 + reg (within 16-row tile)
    #pragma unroll
    for (int t = 0; t < 2; ++t) {
        #pragma unroll
        for (int reg = 0; reg < 4; ++reg) {
            int n = n0 + t * 16 + q * 4 + reg;
            if (n < N_NODES) {
                #pragma unroll
                for (int j = 0; j < 8; ++j)
                    Vh[(size_t)n * DIM + j * 16 + m] = __float2half_rn(acc[t][j][reg]);
                float av = acc[t][8][reg];
                if (m < 8) A1[(size_t)n * NHEADS + m] = av;
                else       A2[(size_t)n * NHEADS + (m - 8)] = av;
            }
        }
    }
}

// ---------------- K3: degree histogram --------------------------------------
__global__ __launch_bounds__(256) void k_hist(
    const int* __restrict__ ei, int* __restrict__ deg) {
    int e = blockIdx.x * 256 + threadIdx.x;
    if (e < N_EDGES) atomicAdd(&deg[ei[N_EDGES + e]], 1);
}

// ---------------- K4a: per-block partial sums of deg ------------------------
__global__ __launch_bounds__(256) void k_scan1(
    const int* __restrict__ deg, int* __restrict__ partial) {
    int t = threadIdx.x;
    int idx = blockIdx.x * 256 + t;
    int v = (idx < N_NODES) ? deg[idx] : 0;
    #pragma unroll
    for (int off = 32; off > 0; off >>= 1) v += __shfl_down(v, off, 64);
    __shared__ int ws_[4];
    if ((t & 63) == 0) ws_[t >> 6] = v;
    __syncthreads();
    if (t == 0) partial[blockIdx.x] = ws_[0] + ws_[1] + ws_[2] + ws_[3];
}

// -------- K4b: per-block local scan; each block also scans the partials -----
__global__ __launch_bounds__(256) void k_scan3(
    const int* __restrict__ deg, const int* __restrict__ partial,
    int* __restrict__ row_off, int* __restrict__ cursor) {
    __shared__ int shp[256];
    __shared__ int sh[256];
    int t = threadIdx.x;
    int pv = (t < NSB) ? partial[t] : 0;
    shp[t] = pv;
    int idx = blockIdx.x * 256 + t;
    int v = (idx < N_NODES) ? deg[idx] : 0;
    sh[t] = v;
    __syncthreads();
    #pragma unroll
    for (int off = 1; off < 256; off <<= 1) {
        int u1 = (t >= off) ? shp[t - off] : 0;
        int u2 = (t >= off) ? sh[t - off] : 0;
        __syncthreads();
        shp[t] += u1;
        sh[t] += u2;
        __syncthreads();
    }
    int pofs = (blockIdx.x == 0) ? 0 : shp[blockIdx.x - 1];
    int excl = sh[t] - v + pofs;
    if (idx < N_NODES) {
        row_off[idx] = excl;
        cursor[idx] = excl;
    }
    if (idx == N_NODES - 1) row_off[N_NODES] = excl + v;   // == N_EDGES
}

// ---------------- K5a: per-chunk per-bin counts (LDS histogram, no atomics) -
__global__ __launch_bounds__(256) void k_count(
    const int* __restrict__ ei, int* __restrict__ cnt) {
    __shared__ int h[NBINS];
    int t = threadIdx.x;
    for (int i = t; i < NBINS; i += 256) h[i] = 0;
    __syncthreads();
    int e0 = blockIdx.x * EPC;
    for (int i = t; i < EPC; i += 256) {
        int dst = ei[N_EDGES + e0 + i];
        atomicAdd(&h[dst / NPB], 1);          // LDS atomic — fast, block-local
    }
    __syncthreads();
    // layout [chunk][bin] so k_place's reload is coalesced
    for (int i = t; i < NBINS; i += 256)
        cnt[(size_t)blockIdx.x * NBINS + i] = h[i];
}

// ---------------- K5b: per-bin scan over chunks; add CSR bin base -----------
// bin base == row_off[bin*NPB] (counting-sort order == CSR order by constr.)
__global__ __launch_bounds__(NCHUNK) void k_scanchunk(
    const int* __restrict__ row_off, const int* __restrict__ cnt,
    int* __restrict__ ofs) {
    __shared__ int sh[NCHUNK];
    int b = blockIdx.x, t = threadIdx.x;
    int v = cnt[(size_t)t * NBINS + b];
    sh[t] = v;
    __syncthreads();
    #pragma unroll
    for (int off = 1; off < NCHUNK; off <<= 1) {
        int u = (t >= off) ? sh[t - off] : 0;
        __syncthreads();
        sh[t] += u;
        __syncthreads();
    }
    int node = b * NPB; if (node > N_NODES) node = N_NODES;
    int base = row_off[node];
    ofs[(size_t)t * NBINS + b] = base + sh[t] - v;   // exclusive
}

// ---------------- K5c: place records into bin regions (LDS cursors) --------
// Each chunk writes ~12 contiguous records per bin -> mostly full-line writes.
__global__ __launch_bounds__(256) void k_place(
    const int* __restrict__ ei, const float* __restrict__ P,
    const float* __restrict__ deter, const int* __restrict__ ofs,
    int2* __restrict__ rec_tmp) {
    __shared__ int cur[NBINS];
    int t = threadIdx.x;
    for (int i = t; i < NBINS; i += 256)
        cur[i] = ofs[(size_t)blockIdx.x * NBINS + i];
    __syncthreads();
    int e0 = blockIdx.x * EPC;
    for (int i = t; i < EPC; i += 256) {
        int e = e0 + i;
        int src = ei[e];
        int dst = ei[N_EDGES + e];
        int pos = atomicAdd(&cur[dst / NPB], 1);   // LDS atomic
        rec_tmp[pos] = make_int2((dst << 16) | src, pack_pd(P[e], deter[e]));
    }
}

// ---------------- K5d: exact scatter within bin (L2-resident window) --------
__global__ __launch_bounds__(256) void k_rebin(
    const int* __restrict__ row_off, const int2* __restrict__ rec_tmp,
    int* __restrict__ cursor, int2* __restrict__ rec) {
    int bin = blockIdx.x;
    int n0 = bin * NPB;       if (n0 > N_NODES) n0 = N_NODES;
    int n1 = n0 + NPB;        if (n1 > N_NODES) n1 = N_NODES;
    int s = row_off[n0];
    int e = row_off[n1];
    for (int i = s + threadIdx.x; i < e; i += 256) {
        int2 r = rec_tmp[i];
        int dst = ((unsigned)r.x) >> 16;
        int src = r.x & 0xFFFF;
        int pos = atomicAdd(&cursor[dst], 1);
        rec[pos] = make_int2(src, r.y);
    }
}

// ---------------- K6: fused softmax + aggregation (4x unrolled) -------------
// wave per node; lane d owns dims (2d, 2d+1) -> head h = d>>3
// writes fp16 result into Xh[n][0:128]
__global__ __launch_bounds__(256) void k_sm_agg(
    const int* __restrict__ row_off, const int2* __restrict__ rec,
    const float* __restrict__ A1, const float* __restrict__ A2,
    const float* __restrict__ cvec, const __half2* __restrict__ Vh2,
    __half* __restrict__ Xh) {
    int n = (blockIdx.x * 256 + threadIdx.x) >> 6;
    int d = threadIdx.x & 63;
    if (n >= N_NODES) return;
    int h = d >> 3;
    float a1 = A1[(size_t)n * NHEADS + h];
    float ch = cvec[h];
    int start = row_off[n], end = row_off[n + 1];
    float s = 0.f, accx = 0.f, accy = 0.f;
    int j = start;
    for (; j + 4 <= end; j += 4) {
        int2 r0 = rec[j], r1 = rec[j + 1], r2 = rec[j + 2], r3 = rec[j + 3];
        int s0 = r0.x, s1 = r1.x, s2 = r2.x, s3 = r3.x;
        float a20 = A2[(size_t)s0 * NHEADS + h];
        float a21 = A2[(size_t)s1 * NHEADS + h];
        float a22 = A2[(size_t)s2 * NHEADS + h];
        float a23 = A2[(size_t)s3 * NHEADS + h];
        __half2 v0 = Vh2[(size_t)s0 * (DIM / 2) + d];
        __half2 v1 = Vh2[(size_t)s1 * (DIM / 2) + d];
        __half2 v2 = Vh2[(size_t)s2 * (DIM / 2) + d];
        __half2 v3 = Vh2[(size_t)s3 * (DIM / 2) + d];
        float2 p0 = unpack_pd(r0.y), p1 = unpack_pd(r1.y);
        float2 p2 = unpack_pd(r2.y), p3 = unpack_pd(r3.y);
        float l0 = a1 + a20 + p0.x * ch + p0.y;
        float l1 = a1 + a21 + p1.x * ch + p1.y;
        float l2 = a1 + a22 + p2.x * ch + p2.y;
        float l3 = a1 + a23 + p3.x * ch + p3.y;
        l0 = (l0 >= 0.f) ? l0 : LEAKY * l0;
        l1 = (l1 >= 0.f) ? l1 : LEAKY * l1;
        l2 = (l2 >= 0.f) ? l2 : LEAKY * l2;
        l3 = (l3 >= 0.f) ? l3 : LEAKY * l3;
        float e0 = __expf(l0), e1 = __expf(l1), e2 = __expf(l2), e3 = __expf(l3);
        s += e0 + e1 + e2 + e3;
        float2 f0 = __half22float2(v0), f1 = __half22float2(v1);
        float2 f2 = __half22float2(v2), f3 = __half22float2(v3);
        accx += e0 * f0.x + e1 * f1.x + e2 * f2.x + e3 * f3.x;
        accy += e0 * f0.y + e1 * f1.y + e2 * f2.y + e3 * f3.y;
    }
    for (; j < end; ++j) {
        int2 r = rec[j];
        int src = r.x;
        float2 pd = unpack_pd(r.y);
        float l = a1 + A2[(size_t)src * NHEADS + h] + pd.x * ch + pd.y;
        l = (l >= 0.f) ? l : LEAKY * l;
        float ex = __expf(l);
        s += ex;
        float2 vf = __half22float2(Vh2[(size_t)src * (DIM / 2) + d]);
        accx += ex * vf.x;
        accy += ex * vf.y;
    }
    float inv = 1.f / (s + 1e-12f);
    __half2 o = __floats2half2_rn(accx * inv, accy * inv);
    *reinterpret_cast<__half2*>(Xh + (size_t)n * 256 + 2 * d) = o;
}

// -- K7: out = Xh(N,256) @ Wch(128,256)^T + bsum, LayerNorm — MFMA -----------
__global__ __launch_bounds__(64) void k_out_mfma(
    const __half* __restrict__ Xh_, const __half* __restrict__ Wch_,
    const float* __restrict__ bsum, const float* __restrict__ ln_g,
    const float* __restrict__ ln_b, float* __restrict__ out) {
    const _Float16* Xh = reinterpret_cast<const _Float16*>(Xh_);
    const _Float16* Wch = reinterpret_cast<const _Float16*>(Wch_);
    int lane = threadIdx.x;          // 0..63
    int m = lane & 15, q = lane >> 4;
    int n0 = blockIdx.x * 32;
    floatx4 z = {0.f, 0.f, 0.f, 0.f};
    floatx4 acc[2][8];
    #pragma unroll
    for (int t = 0; t < 2; ++t)
        #pragma unroll
        for (int j = 0; j < 8; ++j) acc[t][j] = z;
    int r0 = n0 + m;        if (r0 >= N_NODES) r0 = N_NODES - 1;
    int r1 = n0 + 16 + m;   if (r1 >= N_NODES) r1 = N_NODES - 1;
    const _Float16* X0 = Xh + (size_t)r0 * 256 + q * 8;
    const _Float16* X1 = Xh + (size_t)r1 * 256 + q * 8;
    const _Float16* Wb = Wch + (size_t)m * 256 + q * 8;
    #pragma unroll
    for (int ks = 0; ks < 8; ++ks) {
        half8 a0 = *reinterpret_cast<const half8*>(X0 + ks * 32);
        half8 a1 = *reinterpret_cast<const half8*>(X1 + ks * 32);
        #pragma unroll
        for (int j = 0; j < 8; ++j) {
            half8 b = *reinterpret_cast<const half8*>(Wb + (size_t)j * 16 * 256 + ks * 32);
            acc[0][j] = __builtin_amdgcn_mfma_f32_16x16x32_f16(a0, b, acc[0][j], 0, 0, 0);
            acc[1][j] = __builtin_amdgcn_mfma_f32_16x16x32_f16(a1, b, acc[1][j], 0, 0, 0);
        }
    }
    float bsv[8], gv[8], bv[8];
    #pragma unroll
    for (int j = 0; j < 8; ++j) {
        bsv[j] = bsum[j * 16 + m];
        gv[j]  = ln_g[j * 16 + m];
        bv[j]  = ln_b[j * 16 + m];
    }
    #pragma unroll
    for (int t = 0; t < 2; ++t) {
        #pragma unroll
        for (int reg = 0; reg < 4; ++reg) {
            float v[8];
            float s = 0.f, sq = 0.f;
            #pragma unroll
            for (int j = 0; j < 8; ++j) {
                v[j] = acc[t][j][reg] + bsv[j];
                s += v[j];
                sq += v[j] * v[j];
            }
            #pragma unroll
            for (int mk = 1; mk < 16; mk <<= 1) {
                s  += __shfl_xor(s, mk, 64);
                sq += __shfl_xor(sq, mk, 64);
            }
            float mu = s * (1.f / DIM);
            float var = sq * (1.f / DIM) - mu * mu;
            float rs = rsqrtf(var + LN_EPS);
            int n = n0 + t * 16 + q * 4 + reg;
            if (n < N_NODES) {
                #pragma unroll
                for (int j = 0; j < 8; ++j)
                    out[(size_t)n * DIM + j * 16 + m] = (v[j] - mu) * rs * gv[j] + bv[j];
            }
        }
    }
}

// ---------------------------------------------------------------------------
extern "C" void kernel_launch(void* const* d_in, const int* in_sizes, int n_in,
                              void* d_out, int out_size, void* d_ws, size_t ws_size,
                              hipStream_t stream) {
    const float* H      = (const float*)d_in[0];
    const int*   ei     = (const int*)d_in[1];
    const float* P      = (const float*)d_in[2];
    const float* deter  = (const float*)d_in[3];
    const float* W1     = (const float*)d_in[4];
    const float* W2     = (const float*)d_in[5];
    const float* W3     = (const float*)d_in[6];
    const float* W4     = (const float*)d_in[7];
    const float* Wv     = (const float*)d_in[8];
    const float* Wout_w = (const float*)d_in[9];
    const float* Wout_b = (const float*)d_in[10];
    const float* res_w  = (const float*)d_in[11];
    const float* res_b  = (const float*)d_in[12];
    const float* ln_g   = (const float*)d_in[13];
    const float* ln_b   = (const float*)d_in[14];

    float* ws = (float*)d_ws;
    const size_t NH8 = (size_t)N_NODES * NHEADS;   // 400,000

    // ---- workspace layout: IDENTICAL footprint to the known-good baseline --
    __half* Xh  = (__half*)ws;                       // N*256 halves = N*128 words
    float* fbase = ws + (size_t)N_NODES * 128;
    __half* Vh  = (__half*)fbase;                    // N*128 halves = N*64 words
    float* A1   = fbase + (size_t)N_NODES * 64;      // NH8
    float* A2   = A1 + NH8;                          // NH8
    float* cvec = A2 + NH8;                          // 16
    float* bsum = cvec + 16;                         // 128
    __half* Wch  = (__half*)(bsum + 128);            // 128*256 halves = 16384 words
    __half* Wcat = Wch + 128 * 256;                  // 144*128 halves = 9216 words
    int2*  rec  = (int2*)(Wcat + 144 * 128);         // E records (8B each)
    int* deg     = (int*)(rec + N_EDGES);            // N
    int* row_off = deg + N_NODES;                    // N+1
    int* cursor  = row_off + N_NODES + 1;            // N
    int* partial = cursor + N_NODES;                 // 256
    // total ~12.2M words (~49 MB) — same as baseline

    // ---- scratch for the scatter pipeline lives in d_out (25.6 MB):
    //   rec_tmp 6.4 MB + cnt 256 KB + ofs 256 KB = 6.9 MB.
    //   d_out is fully overwritten by k_out_mfma at the end.
    int2* rec_tmp = (int2*)d_out;
    int* cnt = (int*)(rec_tmp + N_EDGES);            // NCHUNK*NBINS ints
    int* ofs = cnt + NCHUNK * NBINS;                 // NCHUNK*NBINS ints

    hipMemsetAsync(deg, 0, N_NODES * sizeof(int), stream);

    k_prep<<<NHEADS, DIM, 0, stream>>>(W1, W2, W3, W4, Wcat, cvec);
    k_wcat<<<DIM, 256, 0, stream>>>(Wout_w, res_w, Wv, Wout_b, res_b, Wch, Wcat, bsum);
    k_node_mfma<<<(N_NODES + 31) / 32, 64, 0, stream>>>(H, Wcat, Vh, Xh, A1, A2);
    k_hist<<<(N_EDGES + 255) / 256, 256, 0, stream>>>(ei, deg);
    k_scan1<<<NSB, 256, 0, stream>>>(deg, partial);
    k_scan3<<<NSB, 256, 0, stream>>>(deg, partial, row_off, cursor);
    k_count<<<NCHUNK, 256, 0, stream>>>(ei, cnt);
    k_scanchunk<<<NBINS, NCHUNK, 0, stream>>>(row_off, cnt, ofs);
    k_place<<<NCHUNK, 256, 0, stream>>>(ei, P, deter, ofs, rec_tmp);
    k_rebin<<<NBINS, 256, 0, stream>>>(row_off, rec_tmp, cursor, rec);
    k_sm_agg<<<(N_NODES + 3) / 4, 256, 0, stream>>>(row_off, rec, A1, A2, cvec,
                                                    (const __half2*)Vh, Xh);
    k_out_mfma<<<(N_NODES + 31) / 32, 64, 0, stream>>>(Xh, Wch, bsum, ln_g, ln_b,
                                                       (float*)d_out);
}

// Round 4
// 247.358 us; speedup vs baseline: 2.0543x; 1.1885x over previous
//
#include <hip/hip_runtime.h>
#include <hip/hip_fp16.h>
#include <math.h>

#define N_NODES 50000
#define N_EDGES 800000
#define DIM 128
#define NHEADS 8
#define LN_EPS 1e-5f
#define LEAKY 0.2f
#define NBINS 512
#define NPB 98     // nodes per bin; 512*98 = 50176 >= N_NODES
#define NCHUNK 256 // edge chunks for counting sort
#define EPC 3125   // edges per chunk; 256*3125 = 800000 exactly

typedef _Float16 half8 __attribute__((ext_vector_type(8)));
typedef float floatx4 __attribute__((ext_vector_type(4)));

// ---------------- pack/unpack (P, deter) as half2 in one int ----------------
__device__ __forceinline__ int pack_pd(float p, float dt) {
    __half2 h = __floats2half2_rn(p, dt);
    int r; __builtin_memcpy(&r, &h, 4); return r;
}
__device__ __forceinline__ float2 unpack_pd(int v) {
    __half2 h; __builtin_memcpy(&h, &v, 4);
    return __half22float2(h);   // .x = P, .y = deter
}

// ------ K1: Wcat rows 128..135 = fp16(W4@W1), 136..143 = fp16(W4@W2); c -----
__global__ __launch_bounds__(128) void k_prep(
    const float* __restrict__ W1, const float* __restrict__ W2,
    const float* __restrict__ W3, const float* __restrict__ W4,
    __half* __restrict__ Wcat, float* __restrict__ c) {
    int h = blockIdx.x;       // 0..7
    int k = threadIdx.x;      // 0..127
    float a1 = 0.f, a2 = 0.f;
    for (int d = 0; d < DIM; ++d) {
        float w4 = W4[h * DIM + d];
        a1 += w4 * W1[d * DIM + k];
        a2 += w4 * W2[d * DIM + k];
    }
    Wcat[(size_t)(128 + h) * DIM + k] = __float2half_rn(a1);
    Wcat[(size_t)(136 + h) * DIM + k] = __float2half_rn(a2);
    __shared__ float red[DIM];
    red[k] = W4[h * DIM + k] * W3[k];
    __syncthreads();
    if (k == 0) {
        float s = 0.f;
        for (int i = 0; i < DIM; ++i) s += red[i];
        c[h] = s;
    }
}

// -- K1b: Wch = fp16[Wout|res_w] (128x256); Wcat rows 0..127 = fp16(Wv); bsum
__global__ __launch_bounds__(256) void k_wcat(
    const float* __restrict__ Wout, const float* __restrict__ Wres,
    const float* __restrict__ Wv, const float* __restrict__ bout,
    const float* __restrict__ bres, __half* __restrict__ Wch,
    __half* __restrict__ Wcat, float* __restrict__ bsum) {
    int d = blockIdx.x;     // 0..127
    int t = threadIdx.x;    // 0..255
    float v = (t < 128) ? Wout[d * 128 + t] : Wres[d * 128 + (t - 128)];
    Wch[(size_t)d * 256 + t] = __float2half_rn(v);
    if (t < 128) Wcat[(size_t)d * DIM + t] = __float2half_rn(Wv[d * 128 + t]);
    if (d == 0 && t < 128) bsum[t] = bout[t] + bres[t];
}

// -- K2: MFMA  Y = H @ Wcat^T  (M=N_NODES, N=144, K=128, fp16 in / fp32 acc) -
//   cols 0..127 -> Vh (fp16), cols 128..135 -> A1, 136..143 -> A2 (fp32)
//   side effect: Xh[:,128:256] = fp16(H)  (converted A-fragments)
__global__ __launch_bounds__(64) void k_node_mfma(
    const float* __restrict__ H, const __half* __restrict__ Wcat_,
    __half* __restrict__ Vh, __half* __restrict__ Xh,
    float* __restrict__ A1, float* __restrict__ A2) {
    const _Float16* Wcat = reinterpret_cast<const _Float16*>(Wcat_);
    int lane = threadIdx.x;          // 0..63
    int m = lane & 15, q = lane >> 4;
    int n0 = blockIdx.x * 32;
    floatx4 z = {0.f, 0.f, 0.f, 0.f};
    floatx4 acc[2][9];
    #pragma unroll
    for (int t = 0; t < 2; ++t)
        #pragma unroll
        for (int j = 0; j < 9; ++j) acc[t][j] = z;
    int r0 = n0 + m;        if (r0 >= N_NODES) r0 = N_NODES - 1;
    int r1 = n0 + 16 + m;   if (r1 >= N_NODES) r1 = N_NODES - 1;
    const float* H0 = H + (size_t)r0 * DIM + q * 8;
    const float* H1 = H + (size_t)r1 * DIM + q * 8;
    _Float16* Xw0 = reinterpret_cast<_Float16*>(Xh) + (size_t)r0 * 256 + 128 + q * 8;
    _Float16* Xw1 = reinterpret_cast<_Float16*>(Xh) + (size_t)r1 * 256 + 128 + q * 8;
    const _Float16* Wb = Wcat + (size_t)m * DIM + q * 8;
    #pragma unroll
    for (int ks = 0; ks < 4; ++ks) {
        float4 fa = *reinterpret_cast<const float4*>(H0 + ks * 32);
        float4 fb = *reinterpret_cast<const float4*>(H0 + ks * 32 + 4);
        float4 ga = *reinterpret_cast<const float4*>(H1 + ks * 32);
        float4 gb = *reinterpret_cast<const float4*>(H1 + ks * 32 + 4);
        half8 a0, a1v;
        a0[0] = (_Float16)fa.x; a0[1] = (_Float16)fa.y;
        a0[2] = (_Float16)fa.z; a0[3] = (_Float16)fa.w;
        a0[4] = (_Float16)fb.x; a0[5] = (_Float16)fb.y;
        a0[6] = (_Float16)fb.z; a0[7] = (_Float16)fb.w;
        a1v[0] = (_Float16)ga.x; a1v[1] = (_Float16)ga.y;
        a1v[2] = (_Float16)ga.z; a1v[3] = (_Float16)ga.w;
        a1v[4] = (_Float16)gb.x; a1v[5] = (_Float16)gb.y;
        a1v[6] = (_Float16)gb.z; a1v[7] = (_Float16)gb.w;
        *reinterpret_cast<half8*>(Xw0 + ks * 32) = a0;
        *reinterpret_cast<half8*>(Xw1 + ks * 32) = a1v;
        #pragma unroll
        for (int j = 0; j < 9; ++j) {
            half8 b = *reinterpret_cast<const half8*>(Wb + (size_t)j * 16 * DIM + ks * 32);
            acc[0][j] = __builtin_amdgcn_mfma_f32_16x16x32_f16(a0, b, acc[0][j], 0, 0, 0);
            acc[1][j] = __builtin_amdgcn_mfma_f32_16x16x32_f16(a1v, b, acc[1][j], 0, 0, 0);
        }
    }
    // C/D layout: col = m, row = q*4 + reg (within 16-row tile)
    #pragma unroll
    for (int t = 0; t < 2; ++t) {
        #pragma unroll
        for (int reg = 0; reg < 4; ++reg) {
            int n = n0 + t * 16 + q * 4 + reg;
            if (n < N_NODES) {
                #pragma unroll
                for (int j = 0; j < 8; ++j)
                    Vh[(size_t)n * DIM + j * 16 + m] = __float2half_rn(acc[t][j][reg]);
                float av = acc[t][8][reg];
                if (m < 8) A1[(size_t)n * NHEADS + m] = av;
                else       A2[(size_t)n * NHEADS + (m - 8)] = av;
            }
        }
    }
}

// ---------------- K5a: per-chunk per-bin counts (LDS histogram) -------------
__global__ __launch_bounds__(256) void k_count(
    const int* __restrict__ ei, int* __restrict__ cnt) {
    __shared__ int h[NBINS];
    int t = threadIdx.x;
    for (int i = t; i < NBINS; i += 256) h[i] = 0;
    __syncthreads();
    int e0 = blockIdx.x * EPC;
    for (int i = t; i < EPC; i += 256) {
        int dst = ei[N_EDGES + e0 + i];
        atomicAdd(&h[dst / NPB], 1);          // LDS atomic — block-local
    }
    __syncthreads();
    // layout [chunk][bin] so k_place's reload is coalesced
    for (int i = t; i < NBINS; i += 256)
        cnt[(size_t)blockIdx.x * NBINS + i] = h[i];
}

// ---------------- K5b: per-bin scan over chunks (relative); bin totals ------
__global__ __launch_bounds__(NCHUNK) void k_scanchunk(
    const int* __restrict__ cnt, int* __restrict__ ofs,
    int* __restrict__ binTot) {
    __shared__ int sh[NCHUNK];
    int b = blockIdx.x, t = threadIdx.x;
    int v = cnt[(size_t)t * NBINS + b];
    sh[t] = v;
    __syncthreads();
    #pragma unroll
    for (int off = 1; off < NCHUNK; off <<= 1) {
        int u = (t >= off) ? sh[t - off] : 0;
        __syncthreads();
        sh[t] += u;
        __syncthreads();
    }
    ofs[(size_t)t * NBINS + b] = sh[t] - v;   // chunk-exclusive, bin-relative
    if (t == NCHUNK - 1) binTot[b] = sh[t];
}

// ---------------- K5c: scan bin totals -> bin bases (one block) -------------
__global__ __launch_bounds__(NBINS) void k_binscan(
    const int* __restrict__ binTot, int* __restrict__ binBase) {
    __shared__ int sh[NBINS];
    int t = threadIdx.x;
    int v = binTot[t];
    sh[t] = v;
    __syncthreads();
    #pragma unroll
    for (int off = 1; off < NBINS; off <<= 1) {
        int u = (t >= off) ? sh[t - off] : 0;
        __syncthreads();
        sh[t] += u;
        __syncthreads();
    }
    binBase[t] = sh[t] - v;                   // exclusive
    if (t == NBINS - 1) binBase[NBINS] = sh[t];   // == N_EDGES
}

// ---------------- K5d: place records into bin regions (LDS cursors) --------
__global__ __launch_bounds__(256) void k_place(
    const int* __restrict__ ei, const float* __restrict__ P,
    const float* __restrict__ deter, const int* __restrict__ ofs,
    const int* __restrict__ binBase, int2* __restrict__ rec_tmp) {
    __shared__ int cur[NBINS];
    int t = threadIdx.x;
    for (int i = t; i < NBINS; i += 256)
        cur[i] = ofs[(size_t)blockIdx.x * NBINS + i] + binBase[i];
    __syncthreads();
    int e0 = blockIdx.x * EPC;
    for (int i = t; i < EPC; i += 256) {
        int e = e0 + i;
        int src = ei[e];
        int dst = ei[N_EDGES + e];
        int pos = atomicAdd(&cur[dst / NPB], 1);   // LDS atomic
        rec_tmp[pos] = make_int2((dst << 16) | src, pack_pd(P[e], deter[e]));
    }
}

// ---- K5e: per-bin: node counts + scan -> row_off; scatter to exact CSR -----
// All LDS-local (98 counters); no global atomics, no k_hist/k_scan needed.
__global__ __launch_bounds__(256) void k_rebin(
    const int* __restrict__ binBase, const int2* __restrict__ rec_tmp,
    int* __restrict__ row_off, int2* __restrict__ rec) {
    __shared__ int cnt_l[NPB];   // counts -> exclusive global offsets
    __shared__ int cur_l[NPB];   // atomic cursors
    int b = blockIdx.x, t = threadIdx.x;
    int s = binBase[b], e = binBase[b + 1];
    int n0 = b * NPB;
    for (int i = t; i < NPB; i += 256) cnt_l[i] = 0;
    __syncthreads();
    for (int i = s + t; i < e; i += 256) {
        int dst = ((unsigned)rec_tmp[i].x) >> 16;
        atomicAdd(&cnt_l[dst - n0], 1);
    }
    __syncthreads();
    if (t == 0) {   // tiny serial scan over 98 entries
        int acc = s;
        for (int i = 0; i < NPB; ++i) {
            int c = cnt_l[i];
            cnt_l[i] = acc;
            cur_l[i] = acc;
            acc += c;
        }
    }
    __syncthreads();
    for (int i = t; i < NPB; i += 256) {
        int n = n0 + i;
        if (n < N_NODES) row_off[n] = cnt_l[i];
    }
    if (b == 0 && t == 0) row_off[N_NODES] = N_EDGES;
    for (int i = s + t; i < e; i += 256) {
        int2 r = rec_tmp[i];
        int dst = ((unsigned)r.x) >> 16;
        int pos = atomicAdd(&cur_l[dst - n0], 1);   // LDS atomic
        rec[pos] = make_int2(r.x & 0xFFFF, r.y);
    }
}

// ---------------- K6: fused softmax + aggregation (8-edge batched) ----------
// wave per node; lane d owns dims (2d, 2d+1) -> head h = d>>3.
// Batch of 8 edges: lane d computes logit/exp for (edge j+(d&7), head d>>3)
// -> one exp per (edge,head) instead of 8 redundant; broadcast e and src
// within each 8-lane group via __shfl(.., k, 8).
__global__ __launch_bounds__(256) void k_sm_agg(
    const int* __restrict__ row_off, const int2* __restrict__ rec,
    const float* __restrict__ A1, const float* __restrict__ A2,
    const float* __restrict__ cvec, const __half2* __restrict__ Vh2,
    __half* __restrict__ Xh) {
    int n = (blockIdx.x * 256 + threadIdx.x) >> 6;
    int d = threadIdx.x & 63;
    if (n >= N_NODES) return;
    int h = d >> 3;
    int k8 = d & 7;
    float a1 = A1[(size_t)n * NHEADS + h];
    float ch = cvec[h];
    int start = row_off[n], end = row_off[n + 1];
    float s = 0.f, accx = 0.f, accy = 0.f;
    for (int j = start; j < end; j += 8) {
        int idx = j + k8;
        int cidx = (idx < end) ? idx : end - 1;
        int2 r = rec[cidx];
        float2 pd = unpack_pd(r.y);
        float a2 = A2[(size_t)r.x * NHEADS + h];
        float l = a1 + a2 + pd.x * ch + pd.y;
        l = (l >= 0.f) ? l : LEAKY * l;
        float ev = (idx < end) ? __expf(l) : 0.f;
        int rem = end - j;                      // wave-uniform
        #pragma unroll
        for (int k = 0; k < 8; ++k) {
            float ek = __shfl(ev, k, 8);        // head-group broadcast
            int srcK = __shfl(r.x, k, 8);       // same edge in every group
            if (k < rem) {
                s += ek;
                float2 vf = __half22float2(Vh2[(size_t)srcK * (DIM / 2) + d]);
                accx += ek * vf.x;
                accy += ek * vf.y;
            }
        }
    }
    float inv = 1.f / (s + 1e-12f);
    __half2 o = __floats2half2_rn(accx * inv, accy * inv);
    *reinterpret_cast<__half2*>(Xh + (size_t)n * 256 + 2 * d) = o;
}

// -- K7: out = Xh(N,256) @ Wch(128,256)^T + bsum, LayerNorm — MFMA -----------
__global__ __launch_bounds__(64) void k_out_mfma(
    const __half* __restrict__ Xh_, const __half* __restrict__ Wch_,
    const float* __restrict__ bsum, const float* __restrict__ ln_g,
    const float* __restrict__ ln_b, float* __restrict__ out) {
    const _Float16* Xh = reinterpret_cast<const _Float16*>(Xh_);
    const _Float16* Wch = reinterpret_cast<const _Float16*>(Wch_);
    int lane = threadIdx.x;          // 0..63
    int m = lane & 15, q = lane >> 4;
    int n0 = blockIdx.x * 32;
    floatx4 z = {0.f, 0.f, 0.f, 0.f};
    floatx4 acc[2][8];
    #pragma unroll
    for (int t = 0; t < 2; ++t)
        #pragma unroll
        for (int j = 0; j < 8; ++j) acc[t][j] = z;
    int r0 = n0 + m;        if (r0 >= N_NODES) r0 = N_NODES - 1;
    int r1 = n0 + 16 + m;   if (r1 >= N_NODES) r1 = N_NODES - 1;
    const _Float16* X0 = Xh + (size_t)r0 * 256 + q * 8;
    const _Float16* X1 = Xh + (size_t)r1 * 256 + q * 8;
    const _Float16* Wb = Wch + (size_t)m * 256 + q * 8;
    #pragma unroll
    for (int ks = 0; ks < 8; ++ks) {
        half8 a0 = *reinterpret_cast<const half8*>(X0 + ks * 32);
        half8 a1 = *reinterpret_cast<const half8*>(X1 + ks * 32);
        #pragma unroll
        for (int j = 0; j < 8; ++j) {
            half8 b = *reinterpret_cast<const half8*>(Wb + (size_t)j * 16 * 256 + ks * 32);
            acc[0][j] = __builtin_amdgcn_mfma_f32_16x16x32_f16(a0, b, acc[0][j], 0, 0, 0);
            acc[1][j] = __builtin_amdgcn_mfma_f32_16x16x32_f16(a1, b, acc[1][j], 0, 0, 0);
        }
    }
    float bsv[8], gv[8], bv[8];
    #pragma unroll
    for (int j = 0; j < 8; ++j) {
        bsv[j] = bsum[j * 16 + m];
        gv[j]  = ln_g[j * 16 + m];
        bv[j]  = ln_b[j * 16 + m];
    }
    #pragma unroll
    for (int t = 0; t < 2; ++t) {
        #pragma unroll
        for (int reg = 0; reg < 4; ++reg) {
            float v[8];
            float s = 0.f, sq = 0.f;
            #pragma unroll
            for (int j = 0; j < 8; ++j) {
                v[j] = acc[t][j][reg] + bsv[j];
                s += v[j];
                sq += v[j] * v[j];
            }
            #pragma unroll
            for (int mk = 1; mk < 16; mk <<= 1) {
                s  += __shfl_xor(s, mk, 64);
                sq += __shfl_xor(sq, mk, 64);
            }
            float mu = s * (1.f / DIM);
            float var = sq * (1.f / DIM) - mu * mu;
            float rs = rsqrtf(var + LN_EPS);
            int n = n0 + t * 16 + q * 4 + reg;
            if (n < N_NODES) {
                #pragma unroll
                for (int j = 0; j < 8; ++j)
                    out[(size_t)n * DIM + j * 16 + m] = (v[j] - mu) * rs * gv[j] + bv[j];
            }
        }
    }
}

// ---------------------------------------------------------------------------
extern "C" void kernel_launch(void* const* d_in, const int* in_sizes, int n_in,
                              void* d_out, int out_size, void* d_ws, size_t ws_size,
                              hipStream_t stream) {
    const float* H      = (const float*)d_in[0];
    const int*   ei     = (const int*)d_in[1];
    const float* P      = (const float*)d_in[2];
    const float* deter  = (const float*)d_in[3];
    const float* W1     = (const float*)d_in[4];
    const float* W2     = (const float*)d_in[5];
    const float* W3     = (const float*)d_in[6];
    const float* W4     = (const float*)d_in[7];
    const float* Wv     = (const float*)d_in[8];
    const float* Wout_w = (const float*)d_in[9];
    const float* Wout_b = (const float*)d_in[10];
    const float* res_w  = (const float*)d_in[11];
    const float* res_b  = (const float*)d_in[12];
    const float* ln_g   = (const float*)d_in[13];
    const float* ln_b   = (const float*)d_in[14];

    float* ws = (float*)d_ws;
    const size_t NH8 = (size_t)N_NODES * NHEADS;   // 400,000

    // ---- workspace layout (subset of the known-good baseline footprint) ----
    __half* Xh  = (__half*)ws;                       // N*256 halves = N*128 words
    float* fbase = ws + (size_t)N_NODES * 128;
    __half* Vh  = (__half*)fbase;                    // N*128 halves = N*64 words
    float* A1   = fbase + (size_t)N_NODES * 64;      // NH8
    float* A2   = A1 + NH8;                          // NH8
    float* cvec = A2 + NH8;                          // 16
    float* bsum = cvec + 16;                         // 128
    __half* Wch  = (__half*)(bsum + 128);            // 128*256 halves = 16384 words
    __half* Wcat = Wch + 128 * 256;                  // 144*128 halves = 9216 words
    int2*  rec  = (int2*)(Wcat + 144 * 128);         // E records (8B each)
    int* row_off = (int*)(rec + N_EDGES);            // N+1
    // total < baseline's ~12.2M words (~49 MB)

    // ---- scratch for the scatter pipeline lives in d_out (25.6 MB):
    //   rec_tmp 6.4 MB + cnt 512 KB + ofs 512 KB + binTot/binBase ~4 KB.
    //   d_out is fully overwritten by k_out_mfma at the end.
    int2* rec_tmp = (int2*)d_out;
    int* cnt     = (int*)(rec_tmp + N_EDGES);        // NCHUNK*NBINS ints
    int* ofs     = cnt + NCHUNK * NBINS;             // NCHUNK*NBINS ints
    int* binTot  = ofs + NCHUNK * NBINS;             // NBINS
    int* binBase = binTot + NBINS;                   // NBINS+1

    k_prep<<<NHEADS, DIM, 0, stream>>>(W1, W2, W3, W4, Wcat, cvec);
    k_wcat<<<DIM, 256, 0, stream>>>(Wout_w, res_w, Wv, Wout_b, res_b, Wch, Wcat, bsum);
    k_node_mfma<<<(N_NODES + 31) / 32, 64, 0, stream>>>(H, Wcat, Vh, Xh, A1, A2);
    k_count<<<NCHUNK, 256, 0, stream>>>(ei, cnt);
    k_scanchunk<<<NBINS, NCHUNK, 0, stream>>>(cnt, ofs, binTot);
    k_binscan<<<1, NBINS, 0, stream>>>(binTot, binBase);
    k_place<<<NCHUNK, 256, 0, stream>>>(ei, P, deter, ofs, binBase, rec_tmp);
    k_rebin<<<NBINS, 256, 0, stream>>>(binBase, rec_tmp, row_off, rec);
    k_sm_agg<<<(N_NODES + 3) / 4, 256, 0, stream>>>(row_off, rec, A1, A2, cvec,
                                                    (const __half2*)Vh, Xh);
    k_out_mfma<<<(N_NODES + 31) / 32, 64, 0, stream>>>(Xh, Wch, bsum, ln_g, ln_b,
                                                       (float*)d_out);
}

// Round 5
// 235.820 us; speedup vs baseline: 2.1548x; 1.0489x over previous
//
#include <hip/hip_runtime.h>
#include <hip/hip_fp16.h>
#include <math.h>

#define N_NODES 50000
#define N_EDGES 800000
#define DIM 128
#define NHEADS 8
#define LN_EPS 1e-5f
#define LEAKY 0.2f
#define NBINS 512
#define NPB 98     // nodes per bin; 512*98 = 50176 >= N_NODES
#define NCHUNK 256 // edge chunks for counting sort
#define EPC 3125   // edges per chunk; 256*3125 = 800000 exactly

typedef _Float16 half8 __attribute__((ext_vector_type(8)));
typedef float floatx4 __attribute__((ext_vector_type(4)));

// ---------------- pack/unpack (P, deter) as half2 in one int ----------------
__device__ __forceinline__ int pack_pd(float p, float dt) {
    __half2 h = __floats2half2_rn(p, dt);
    int r; __builtin_memcpy(&r, &h, 4); return r;
}
__device__ __forceinline__ float2 unpack_pd(int v) {
    __half2 h; __builtin_memcpy(&h, &v, 4);
    return __half22float2(h);   // .x = P, .y = deter
}

// ------ K1: Wcat rows 128..135 = fp16(W4@W1), 136..143 = fp16(W4@W2); c -----
__global__ __launch_bounds__(128) void k_prep(
    const float* __restrict__ W1, const float* __restrict__ W2,
    const float* __restrict__ W3, const float* __restrict__ W4,
    __half* __restrict__ Wcat, float* __restrict__ c) {
    int h = blockIdx.x;       // 0..7
    int k = threadIdx.x;      // 0..127
    float a1 = 0.f, a2 = 0.f;
    for (int d = 0; d < DIM; ++d) {
        float w4 = W4[h * DIM + d];
        a1 += w4 * W1[d * DIM + k];
        a2 += w4 * W2[d * DIM + k];
    }
    Wcat[(size_t)(128 + h) * DIM + k] = __float2half_rn(a1);
    Wcat[(size_t)(136 + h) * DIM + k] = __float2half_rn(a2);
    __shared__ float red[DIM];
    red[k] = W4[h * DIM + k] * W3[k];
    __syncthreads();
    if (k == 0) {
        float s = 0.f;
        for (int i = 0; i < DIM; ++i) s += red[i];
        c[h] = s;
    }
}

// -- K1b: Wch = fp16[Wout|res_w] (128x256); Wcat rows 0..127 = fp16(Wv); bsum
__global__ __launch_bounds__(256) void k_wcat(
    const float* __restrict__ Wout, const float* __restrict__ Wres,
    const float* __restrict__ Wv, const float* __restrict__ bout,
    const float* __restrict__ bres, __half* __restrict__ Wch,
    __half* __restrict__ Wcat, float* __restrict__ bsum) {
    int d = blockIdx.x;     // 0..127
    int t = threadIdx.x;    // 0..255
    float v = (t < 128) ? Wout[d * 128 + t] : Wres[d * 128 + (t - 128)];
    Wch[(size_t)d * 256 + t] = __float2half_rn(v);
    if (t < 128) Wcat[(size_t)d * DIM + t] = __float2half_rn(Wv[d * 128 + t]);
    if (d == 0 && t < 128) bsum[t] = bout[t] + bres[t];
}

// -- K2: MFMA  Y = H @ Wcat^T  (M=N_NODES, N=144, K=128, fp16 in / fp32 acc) -
//   cols 0..127 -> Vh (fp16), cols 128..135 -> A1, 136..143 -> A2 (fp32)
//   side effect: Xh[:,128:256] = fp16(H)  (converted A-fragments)
__global__ __launch_bounds__(64) void k_node_mfma(
    const float* __restrict__ H, const __half* __restrict__ Wcat_,
    __half* __restrict__ Vh, __half* __restrict__ Xh,
    float* __restrict__ A1, float* __restrict__ A2) {
    const _Float16* Wcat = reinterpret_cast<const _Float16*>(Wcat_);
    int lane = threadIdx.x;          // 0..63
    int m = lane & 15, q = lane >> 4;
    int n0 = blockIdx.x * 32;
    floatx4 z = {0.f, 0.f, 0.f, 0.f};
    floatx4 acc[2][9];
    #pragma unroll
    for (int t = 0; t < 2; ++t)
        #pragma unroll
        for (int j = 0; j < 9; ++j) acc[t][j] = z;
    int r0 = n0 + m;        if (r0 >= N_NODES) r0 = N_NODES - 1;
    int r1 = n0 + 16 + m;   if (r1 >= N_NODES) r1 = N_NODES - 1;
    const float* H0 = H + (size_t)r0 * DIM + q * 8;
    const float* H1 = H + (size_t)r1 * DIM + q * 8;
    _Float16* Xw0 = reinterpret_cast<_Float16*>(Xh) + (size_t)r0 * 256 + 128 + q * 8;
    _Float16* Xw1 = reinterpret_cast<_Float16*>(Xh) + (size_t)r1 * 256 + 128 + q * 8;
    const _Float16* Wb = Wcat + (size_t)m * DIM + q * 8;
    #pragma unroll
    for (int ks = 0; ks < 4; ++ks) {
        float4 fa = *reinterpret_cast<const float4*>(H0 + ks * 32);
        float4 fb = *reinterpret_cast<const float4*>(H0 + ks * 32 + 4);
        float4 ga = *reinterpret_cast<const float4*>(H1 + ks * 32);
        float4 gb = *reinterpret_cast<const float4*>(H1 + ks * 32 + 4);
        half8 a0, a1v;
        a0[0] = (_Float16)fa.x; a0[1] = (_Float16)fa.y;
        a0[2] = (_Float16)fa.z; a0[3] = (_Float16)fa.w;
        a0[4] = (_Float16)fb.x; a0[5] = (_Float16)fb.y;
        a0[6] = (_Float16)fb.z; a0[7] = (_Float16)fb.w;
        a1v[0] = (_Float16)ga.x; a1v[1] = (_Float16)ga.y;
        a1v[2] = (_Float16)ga.z; a1v[3] = (_Float16)ga.w;
        a1v[4] = (_Float16)gb.x; a1v[5] = (_Float16)gb.y;
        a1v[6] = (_Float16)gb.z; a1v[7] = (_Float16)gb.w;
        *reinterpret_cast<half8*>(Xw0 + ks * 32) = a0;
        *reinterpret_cast<half8*>(Xw1 + ks * 32) = a1v;
        #pragma unroll
        for (int j = 0; j < 9; ++j) {
            half8 b = *reinterpret_cast<const half8*>(Wb + (size_t)j * 16 * DIM + ks * 32);
            acc[0][j] = __builtin_amdgcn_mfma_f32_16x16x32_f16(a0, b, acc[0][j], 0, 0, 0);
            acc[1][j] = __builtin_amdgcn_mfma_f32_16x16x32_f16(a1v, b, acc[1][j], 0, 0, 0);
        }
    }
    // C/D layout: col = m, row = q*4 + reg (within 16-row tile)
    #pragma unroll
    for (int t = 0; t < 2; ++t) {
        #pragma unroll
        for (int reg = 0; reg < 4; ++reg) {
            int n = n0 + t * 16 + q * 4 + reg;
            if (n < N_NODES) {
                #pragma unroll
                for (int j = 0; j < 8; ++j)
                    Vh[(size_t)n * DIM + j * 16 + m] = __float2half_rn(acc[t][j][reg]);
                float av = acc[t][8][reg];
                if (m < 8) A1[(size_t)n * NHEADS + m] = av;
                else       A2[(size_t)n * NHEADS + (m - 8)] = av;
            }
        }
    }
}

// ---------------- K5a: per-chunk per-bin counts (LDS histogram) -------------
__global__ __launch_bounds__(256) void k_count(
    const int* __restrict__ ei, int* __restrict__ cnt) {
    __shared__ int h[NBINS];
    int t = threadIdx.x;
    for (int i = t; i < NBINS; i += 256) h[i] = 0;
    __syncthreads();
    int e0 = blockIdx.x * EPC;
    for (int i = t; i < EPC; i += 256) {
        int dst = ei[N_EDGES + e0 + i];
        atomicAdd(&h[dst / NPB], 1);          // LDS atomic — block-local
    }
    __syncthreads();
    // layout [chunk][bin] so k_place's reload is coalesced
    for (int i = t; i < NBINS; i += 256)
        cnt[(size_t)blockIdx.x * NBINS + i] = h[i];
}

// ---------------- K5b: per-bin scan over chunks (relative); bin totals ------
__global__ __launch_bounds__(NCHUNK) void k_scanchunk(
    const int* __restrict__ cnt, int* __restrict__ ofs,
    int* __restrict__ binTot) {
    __shared__ int sh[NCHUNK];
    int b = blockIdx.x, t = threadIdx.x;
    int v = cnt[(size_t)t * NBINS + b];
    sh[t] = v;
    __syncthreads();
    #pragma unroll
    for (int off = 1; off < NCHUNK; off <<= 1) {
        int u = (t >= off) ? sh[t - off] : 0;
        __syncthreads();
        sh[t] += u;
        __syncthreads();
    }
    ofs[(size_t)t * NBINS + b] = sh[t] - v;   // chunk-exclusive, bin-relative
    if (t == NCHUNK - 1) binTot[b] = sh[t];
}

// ---------------- K5c: scan bin totals -> bin bases (one block) -------------
__global__ __launch_bounds__(NBINS) void k_binscan(
    const int* __restrict__ binTot, int* __restrict__ binBase) {
    __shared__ int sh[NBINS];
    int t = threadIdx.x;
    int v = binTot[t];
    sh[t] = v;
    __syncthreads();
    #pragma unroll
    for (int off = 1; off < NBINS; off <<= 1) {
        int u = (t >= off) ? sh[t - off] : 0;
        __syncthreads();
        sh[t] += u;
        __syncthreads();
    }
    binBase[t] = sh[t] - v;                   // exclusive
    if (t == NBINS - 1) binBase[NBINS] = sh[t];   // == N_EDGES
}

// ---------------- K5d: place records into bin regions (LDS cursors) --------
__global__ __launch_bounds__(256) void k_place(
    const int* __restrict__ ei, const float* __restrict__ P,
    const float* __restrict__ deter, const int* __restrict__ ofs,
    const int* __restrict__ binBase, int2* __restrict__ rec_tmp) {
    __shared__ int cur[NBINS];
    int t = threadIdx.x;
    for (int i = t; i < NBINS; i += 256)
        cur[i] = ofs[(size_t)blockIdx.x * NBINS + i] + binBase[i];
    __syncthreads();
    int e0 = blockIdx.x * EPC;
    for (int i = t; i < EPC; i += 256) {
        int e = e0 + i;
        int src = ei[e];
        int dst = ei[N_EDGES + e];
        int pos = atomicAdd(&cur[dst / NPB], 1);   // LDS atomic
        rec_tmp[pos] = make_int2((dst << 16) | src, pack_pd(P[e], deter[e]));
    }
}

// ---- K5e: per-bin: node counts + scan -> row_off; scatter to exact CSR -----
// All LDS-local (98 counters); keeps dst in rec for the edge-exp pass.
__global__ __launch_bounds__(256) void k_rebin(
    const int* __restrict__ binBase, const int2* __restrict__ rec_tmp,
    int* __restrict__ row_off, int2* __restrict__ rec) {
    __shared__ int cnt_l[NPB];   // counts -> exclusive global offsets
    __shared__ int cur_l[NPB];   // atomic cursors
    int b = blockIdx.x, t = threadIdx.x;
    int s = binBase[b], e = binBase[b + 1];
    int n0 = b * NPB;
    for (int i = t; i < NPB; i += 256) cnt_l[i] = 0;
    __syncthreads();
    for (int i = s + t; i < e; i += 256) {
        int dst = ((unsigned)rec_tmp[i].x) >> 16;
        atomicAdd(&cnt_l[dst - n0], 1);
    }
    __syncthreads();
    if (t == 0) {   // tiny serial scan over 98 entries
        int acc = s;
        for (int i = 0; i < NPB; ++i) {
            int c = cnt_l[i];
            cnt_l[i] = acc;
            cur_l[i] = acc;
            acc += c;
        }
    }
    __syncthreads();
    for (int i = t; i < NPB; i += 256) {
        int n = n0 + i;
        if (n < N_NODES) row_off[n] = cnt_l[i];
    }
    if (b == 0 && t == 0) row_off[N_NODES] = N_EDGES;
    for (int i = s + t; i < e; i += 256) {
        int2 r = rec_tmp[i];
        int dst = ((unsigned)r.x) >> 16;
        int pos = atomicAdd(&cur_l[dst - n0], 1);   // LDS atomic
        rec[pos] = r;                               // keep dst|src + pd
    }
}

// ---- K6a: edge-parallel exp: w[e][h] = fp16(exp(leaky(logit) - 4)) --------
// One thread per edge computes all 8 heads. The -4 bias cancels in the
// softmax ratio and keeps exp() well inside fp16 range.
__global__ __launch_bounds__(256) void k_edge_exp(
    const int2* __restrict__ rec, const float* __restrict__ A1,
    const float* __restrict__ A2, const float* __restrict__ cvec,
    __half* __restrict__ w) {
    __shared__ float cs[NHEADS];
    int t = threadIdx.x;
    if (t < NHEADS) cs[t] = cvec[t];
    __syncthreads();
    int e = blockIdx.x * 256 + t;
    if (e >= N_EDGES) return;
    int2 r = rec[e];
    int dst = ((unsigned)r.x) >> 16;
    int src = r.x & 0xFFFF;
    float2 pd = unpack_pd(r.y);
    float4 a1lo = *reinterpret_cast<const float4*>(A1 + (size_t)dst * NHEADS);
    float4 a1hi = *reinterpret_cast<const float4*>(A1 + (size_t)dst * NHEADS + 4);
    float4 a2lo = *reinterpret_cast<const float4*>(A2 + (size_t)src * NHEADS);
    float4 a2hi = *reinterpret_cast<const float4*>(A2 + (size_t)src * NHEADS + 4);
    float a1v[8] = {a1lo.x, a1lo.y, a1lo.z, a1lo.w, a1hi.x, a1hi.y, a1hi.z, a1hi.w};
    float a2v[8] = {a2lo.x, a2lo.y, a2lo.z, a2lo.w, a2hi.x, a2hi.y, a2hi.z, a2hi.w};
    half8 o;
    #pragma unroll
    for (int h = 0; h < NHEADS; ++h) {
        float l = a1v[h] + a2v[h] + pd.x * cs[h] + pd.y;
        l = (l >= 0.f) ? l : LEAKY * l;
        o[h] = (_Float16)__expf(l - 4.0f);
    }
    *reinterpret_cast<half8*>(w + (size_t)e * NHEADS) = o;
}

// ---- K6b: aggregation: high-MLP gather of w-weighted V rows ---------------
// wave per node; lane d owns dims (2d, 2d+1), head h = d>>3.
// Per edge: broadcast 2B w load + 4B V gather + 2 FMA. No shfl, no exp.
__global__ __launch_bounds__(256) void k_agg(
    const int* __restrict__ row_off, const int2* __restrict__ rec,
    const __half* __restrict__ w, const __half2* __restrict__ Vh2,
    __half* __restrict__ Xh) {
    int n = (blockIdx.x * 256 + threadIdx.x) >> 6;
    int d = threadIdx.x & 63;
    if (n >= N_NODES) return;
    int h = d >> 3;
    int start = row_off[n], end = row_off[n + 1];
    float s = 0.f, accx = 0.f, accy = 0.f;
    int j = start;
    for (; j + 4 <= end; j += 4) {
        int s0 = rec[j].x & 0xFFFF;
        int s1 = rec[j + 1].x & 0xFFFF;
        int s2 = rec[j + 2].x & 0xFFFF;
        int s3 = rec[j + 3].x & 0xFFFF;
        float w0 = __half2float(w[(size_t)(j + 0) * NHEADS + h]);
        float w1 = __half2float(w[(size_t)(j + 1) * NHEADS + h]);
        float w2 = __half2float(w[(size_t)(j + 2) * NHEADS + h]);
        float w3 = __half2float(w[(size_t)(j + 3) * NHEADS + h]);
        __half2 v0 = Vh2[(size_t)s0 * (DIM / 2) + d];
        __half2 v1 = Vh2[(size_t)s1 * (DIM / 2) + d];
        __half2 v2 = Vh2[(size_t)s2 * (DIM / 2) + d];
        __half2 v3 = Vh2[(size_t)s3 * (DIM / 2) + d];
        s += w0 + w1 + w2 + w3;
        float2 f0 = __half22float2(v0), f1 = __half22float2(v1);
        float2 f2 = __half22float2(v2), f3 = __half22float2(v3);
        accx += w0 * f0.x + w1 * f1.x + w2 * f2.x + w3 * f3.x;
        accy += w0 * f0.y + w1 * f1.y + w2 * f2.y + w3 * f3.y;
    }
    for (; j < end; ++j) {
        int src = rec[j].x & 0xFFFF;
        float wv = __half2float(w[(size_t)j * NHEADS + h]);
        s += wv;
        float2 vf = __half22float2(Vh2[(size_t)src * (DIM / 2) + d]);
        accx += wv * vf.x;
        accy += wv * vf.y;
    }
    float inv = 1.f / (s + 1e-12f);
    __half2 o = __floats2half2_rn(accx * inv, accy * inv);
    *reinterpret_cast<__half2*>(Xh + (size_t)n * 256 + 2 * d) = o;
}

// -- K7: out = Xh(N,256) @ Wch(128,256)^T + bsum, LayerNorm — MFMA -----------
__global__ __launch_bounds__(64) void k_out_mfma(
    const __half* __restrict__ Xh_, const __half* __restrict__ Wch_,
    const float* __restrict__ bsum, const float* __restrict__ ln_g,
    const float* __restrict__ ln_b, float* __restrict__ out) {
    const _Float16* Xh = reinterpret_cast<const _Float16*>(Xh_);
    const _Float16* Wch = reinterpret_cast<const _Float16*>(Wch_);
    int lane = threadIdx.x;          // 0..63
    int m = lane & 15, q = lane >> 4;
    int n0 = blockIdx.x * 32;
    floatx4 z = {0.f, 0.f, 0.f, 0.f};
    floatx4 acc[2][8];
    #pragma unroll
    for (int t = 0; t < 2; ++t)
        #pragma unroll
        for (int j = 0; j < 8; ++j) acc[t][j] = z;
    int r0 = n0 + m;        if (r0 >= N_NODES) r0 = N_NODES - 1;
    int r1 = n0 + 16 + m;   if (r1 >= N_NODES) r1 = N_NODES - 1;
    const _Float16* X0 = Xh + (size_t)r0 * 256 + q * 8;
    const _Float16* X1 = Xh + (size_t)r1 * 256 + q * 8;
    const _Float16* Wb = Wch + (size_t)m * 256 + q * 8;
    #pragma unroll
    for (int ks = 0; ks < 8; ++ks) {
        half8 a0 = *reinterpret_cast<const half8*>(X0 + ks * 32);
        half8 a1 = *reinterpret_cast<const half8*>(X1 + ks * 32);
        #pragma unroll
        for (int j = 0; j < 8; ++j) {
            half8 b = *reinterpret_cast<const half8*>(Wb + (size_t)j * 16 * 256 + ks * 32);
            acc[0][j] = __builtin_amdgcn_mfma_f32_16x16x32_f16(a0, b, acc[0][j], 0, 0, 0);
            acc[1][j] = __builtin_amdgcn_mfma_f32_16x16x32_f16(a1, b, acc[1][j], 0, 0, 0);
        }
    }
    float bsv[8], gv[8], bv[8];
    #pragma unroll
    for (int j = 0; j < 8; ++j) {
        bsv[j] = bsum[j * 16 + m];
        gv[j]  = ln_g[j * 16 + m];
        bv[j]  = ln_b[j * 16 + m];
    }
    #pragma unroll
    for (int t = 0; t < 2; ++t) {
        #pragma unroll
        for (int reg = 0; reg < 4; ++reg) {
            float v[8];
            float s = 0.f, sq = 0.f;
            #pragma unroll
            for (int j = 0; j < 8; ++j) {
                v[j] = acc[t][j][reg] + bsv[j];
                s += v[j];
                sq += v[j] * v[j];
            }
            #pragma unroll
            for (int mk = 1; mk < 16; mk <<= 1) {
                s  += __shfl_xor(s, mk, 64);
                sq += __shfl_xor(sq, mk, 64);
            }
            float mu = s * (1.f / DIM);
            float var = sq * (1.f / DIM) - mu * mu;
            float rs = rsqrtf(var + LN_EPS);
            int n = n0 + t * 16 + q * 4 + reg;
            if (n < N_NODES) {
                #pragma unroll
                for (int j = 0; j < 8; ++j)
                    out[(size_t)n * DIM + j * 16 + m] = (v[j] - mu) * rs * gv[j] + bv[j];
            }
        }
    }
}

// ---------------------------------------------------------------------------
extern "C" void kernel_launch(void* const* d_in, const int* in_sizes, int n_in,
                              void* d_out, int out_size, void* d_ws, size_t ws_size,
                              hipStream_t stream) {
    const float* H      = (const float*)d_in[0];
    const int*   ei     = (const int*)d_in[1];
    const float* P      = (const float*)d_in[2];
    const float* deter  = (const float*)d_in[3];
    const float* W1     = (const float*)d_in[4];
    const float* W2     = (const float*)d_in[5];
    const float* W3     = (const float*)d_in[6];
    const float* W4     = (const float*)d_in[7];
    const float* Wv     = (const float*)d_in[8];
    const float* Wout_w = (const float*)d_in[9];
    const float* Wout_b = (const float*)d_in[10];
    const float* res_w  = (const float*)d_in[11];
    const float* res_b  = (const float*)d_in[12];
    const float* ln_g   = (const float*)d_in[13];
    const float* ln_b   = (const float*)d_in[14];

    float* ws = (float*)d_ws;
    const size_t NH8 = (size_t)N_NODES * NHEADS;   // 400,000

    // ---- workspace layout (subset of the known-good baseline footprint) ----
    __half* Xh  = (__half*)ws;                       // N*256 halves = N*128 words
    float* fbase = ws + (size_t)N_NODES * 128;
    __half* Vh  = (__half*)fbase;                    // N*128 halves = N*64 words
    float* A1   = fbase + (size_t)N_NODES * 64;      // NH8
    float* A2   = A1 + NH8;                          // NH8
    float* cvec = A2 + NH8;                          // 16
    float* bsum = cvec + 16;                         // 128
    __half* Wch  = (__half*)(bsum + 128);            // 128*256 halves = 16384 words
    __half* Wcat = Wch + 128 * 256;                  // 144*128 halves = 9216 words
    int2*  rec  = (int2*)(Wcat + 144 * 128);         // E records (8B each)
    int* row_off = (int*)(rec + N_EDGES);            // N+1
    // total < baseline's ~12.2M words (~49 MB)

    // ---- scratch in d_out (25.6 MB): rec_tmp 6.4 + cnt 0.5 + ofs 0.5 +
    //      binTot/binBase ~4 KB + w 12.8 = ~20.3 MB.
    //      d_out is fully overwritten by k_out_mfma at the end.
    int2* rec_tmp = (int2*)d_out;
    int* cnt     = (int*)(rec_tmp + N_EDGES);        // NCHUNK*NBINS ints
    int* ofs     = cnt + NCHUNK * NBINS;             // NCHUNK*NBINS ints
    int* binTot  = ofs + NCHUNK * NBINS;             // NBINS
    int* binBase = binTot + NBINS;                   // NBINS+1
    __half* w    = (__half*)(binBase + NBINS + 1);   // E*8 halves = 12.8 MB

    k_prep<<<NHEADS, DIM, 0, stream>>>(W1, W2, W3, W4, Wcat, cvec);
    k_wcat<<<DIM, 256, 0, stream>>>(Wout_w, res_w, Wv, Wout_b, res_b, Wch, Wcat, bsum);
    k_node_mfma<<<(N_NODES + 31) / 32, 64, 0, stream>>>(H, Wcat, Vh, Xh, A1, A2);
    k_count<<<NCHUNK, 256, 0, stream>>>(ei, cnt);
    k_scanchunk<<<NBINS, NCHUNK, 0, stream>>>(cnt, ofs, binTot);
    k_binscan<<<1, NBINS, 0, stream>>>(binTot, binBase);
    k_place<<<NCHUNK, 256, 0, stream>>>(ei, P, deter, ofs, binBase, rec_tmp);
    k_rebin<<<NBINS, 256, 0, stream>>>(binBase, rec_tmp, row_off, rec);
    k_edge_exp<<<(N_EDGES + 255) / 256, 256, 0, stream>>>(rec, A1, A2, cvec, w);
    k_agg<<<(N_NODES + 3) / 4, 256, 0, stream>>>(row_off, rec, w,
                                                 (const __half2*)Vh, Xh);
    k_out_mfma<<<(N_NODES + 31) / 32, 64, 0, stream>>>(Xh, Wch, bsum, ln_g, ln_b,
                                                       (float*)d_out);
}

// Round 6
// 228.836 us; speedup vs baseline: 2.2206x; 1.0305x over previous
//
#include <hip/hip_runtime.h>
#include <hip/hip_fp16.h>
#include <math.h>

#define N_NODES 50000
#define N_EDGES 800000
#define DIM 128
#define NHEADS 8
#define LN_EPS 1e-5f
#define LEAKY 0.2f
#define NBINS 512
#define NPB 98     // nodes per bin; 512*98 = 50176 >= N_NODES
#define NCHUNK 256 // edge chunks for counting sort
#define EPC 3125   // edges per chunk; 256*3125 = 800000 exactly

typedef _Float16 half8 __attribute__((ext_vector_type(8)));
typedef float floatx4 __attribute__((ext_vector_type(4)));

// ---------------- pack/unpack (P, deter) as half2 in one int ----------------
__device__ __forceinline__ int pack_pd(float p, float dt) {
    __half2 h = __floats2half2_rn(p, dt);
    int r; __builtin_memcpy(&r, &h, 4); return r;
}
__device__ __forceinline__ float2 unpack_pd(int v) {
    __half2 h; __builtin_memcpy(&h, &v, 4);
    return __half22float2(h);   // .x = P, .y = deter
}

// -- K1 (fused): blocks 0..127 -> Wch/Wcat[0:128]/bsum; 128..135 -> attn rows
__global__ __launch_bounds__(256) void k_weights(
    const float* __restrict__ W1, const float* __restrict__ W2,
    const float* __restrict__ W3, const float* __restrict__ W4,
    const float* __restrict__ Wout, const float* __restrict__ Wres,
    const float* __restrict__ Wv, const float* __restrict__ bout,
    const float* __restrict__ bres, __half* __restrict__ Wch,
    __half* __restrict__ Wcat, float* __restrict__ bsum,
    float* __restrict__ c) {
    int b = blockIdx.x;
    int t = threadIdx.x;
    if (b < 128) {
        int d = b;
        float v = (t < 128) ? Wout[d * 128 + t] : Wres[d * 128 + (t - 128)];
        Wch[(size_t)d * 256 + t] = __float2half_rn(v);
        if (t < 128) Wcat[(size_t)d * DIM + t] = __float2half_rn(Wv[d * 128 + t]);
        if (d == 0 && t < 128) bsum[t] = bout[t] + bres[t];
    } else {
        int h = b - 128;          // 0..7
        if (t < 128) {
            int k = t;
            float a1 = 0.f, a2 = 0.f;
            for (int d = 0; d < DIM; ++d) {
                float w4 = W4[h * DIM + d];
                a1 += w4 * W1[d * DIM + k];
                a2 += w4 * W2[d * DIM + k];
            }
            Wcat[(size_t)(128 + h) * DIM + k] = __float2half_rn(a1);
            Wcat[(size_t)(136 + h) * DIM + k] = __float2half_rn(a2);
        }
        __shared__ float red[DIM];
        if (t < 128) red[t] = W4[h * DIM + t] * W3[t];
        __syncthreads();
        if (t == 0) {
            float s = 0.f;
            for (int i = 0; i < DIM; ++i) s += red[i];
            c[h] = s;
        }
    }
}

// -- K2: MFMA  Y = H @ Wcat^T  (M=N_NODES, N=144, K=128, fp16 in / fp32 acc) -
//   cols 0..127 -> Vh (fp16), cols 128..135 -> A1, 136..143 -> A2 (fp32)
//   side effect: Xh[:,128:256] = fp16(H)  (converted A-fragments)
__global__ __launch_bounds__(64) void k_node_mfma(
    const float* __restrict__ H, const __half* __restrict__ Wcat_,
    __half* __restrict__ Vh, __half* __restrict__ Xh,
    float* __restrict__ A1, float* __restrict__ A2) {
    const _Float16* Wcat = reinterpret_cast<const _Float16*>(Wcat_);
    int lane = threadIdx.x;          // 0..63
    int m = lane & 15, q = lane >> 4;
    int n0 = blockIdx.x * 32;
    floatx4 z = {0.f, 0.f, 0.f, 0.f};
    floatx4 acc[2][9];
    #pragma unroll
    for (int t = 0; t < 2; ++t)
        #pragma unroll
        for (int j = 0; j < 9; ++j) acc[t][j] = z;
    int r0 = n0 + m;        if (r0 >= N_NODES) r0 = N_NODES - 1;
    int r1 = n0 + 16 + m;   if (r1 >= N_NODES) r1 = N_NODES - 1;
    const float* H0 = H + (size_t)r0 * DIM + q * 8;
    const float* H1 = H + (size_t)r1 * DIM + q * 8;
    _Float16* Xw0 = reinterpret_cast<_Float16*>(Xh) + (size_t)r0 * 256 + 128 + q * 8;
    _Float16* Xw1 = reinterpret_cast<_Float16*>(Xh) + (size_t)r1 * 256 + 128 + q * 8;
    const _Float16* Wb = Wcat + (size_t)m * DIM + q * 8;
    #pragma unroll
    for (int ks = 0; ks < 4; ++ks) {
        float4 fa = *reinterpret_cast<const float4*>(H0 + ks * 32);
        float4 fb = *reinterpret_cast<const float4*>(H0 + ks * 32 + 4);
        float4 ga = *reinterpret_cast<const float4*>(H1 + ks * 32);
        float4 gb = *reinterpret_cast<const float4*>(H1 + ks * 32 + 4);
        half8 a0, a1v;
        a0[0] = (_Float16)fa.x; a0[1] = (_Float16)fa.y;
        a0[2] = (_Float16)fa.z; a0[3] = (_Float16)fa.w;
        a0[4] = (_Float16)fb.x; a0[5] = (_Float16)fb.y;
        a0[6] = (_Float16)fb.z; a0[7] = (_Float16)fb.w;
        a1v[0] = (_Float16)ga.x; a1v[1] = (_Float16)ga.y;
        a1v[2] = (_Float16)ga.z; a1v[3] = (_Float16)ga.w;
        a1v[4] = (_Float16)gb.x; a1v[5] = (_Float16)gb.y;
        a1v[6] = (_Float16)gb.z; a1v[7] = (_Float16)gb.w;
        *reinterpret_cast<half8*>(Xw0 + ks * 32) = a0;
        *reinterpret_cast<half8*>(Xw1 + ks * 32) = a1v;
        #pragma unroll
        for (int j = 0; j < 9; ++j) {
            half8 b = *reinterpret_cast<const half8*>(Wb + (size_t)j * 16 * DIM + ks * 32);
            acc[0][j] = __builtin_amdgcn_mfma_f32_16x16x32_f16(a0, b, acc[0][j], 0, 0, 0);
            acc[1][j] = __builtin_amdgcn_mfma_f32_16x16x32_f16(a1v, b, acc[1][j], 0, 0, 0);
        }
    }
    // C/D layout: col = m, row = q*4 + reg (within 16-row tile)
    #pragma unroll
    for (int t = 0; t < 2; ++t) {
        #pragma unroll
        for (int reg = 0; reg < 4; ++reg) {
            int n = n0 + t * 16 + q * 4 + reg;
            if (n < N_NODES) {
                #pragma unroll
                for (int j = 0; j < 8; ++j)
                    Vh[(size_t)n * DIM + j * 16 + m] = __float2half_rn(acc[t][j][reg]);
                float av = acc[t][8][reg];
                if (m < 8) A1[(size_t)n * NHEADS + m] = av;
                else       A2[(size_t)n * NHEADS + (m - 8)] = av;
            }
        }
    }
}

// ---------------- K5a: per-chunk per-bin counts (LDS histogram) -------------
__global__ __launch_bounds__(256) void k_count(
    const int* __restrict__ ei, int* __restrict__ cnt) {
    __shared__ int h[NBINS];
    int t = threadIdx.x;
    for (int i = t; i < NBINS; i += 256) h[i] = 0;
    __syncthreads();
    int e0 = blockIdx.x * EPC;
    for (int i = t; i < EPC; i += 256) {
        int dst = ei[N_EDGES + e0 + i];
        atomicAdd(&h[dst / NPB], 1);          // LDS atomic — block-local
    }
    __syncthreads();
    // layout [chunk][bin] so k_place's reload is coalesced
    for (int i = t; i < NBINS; i += 256)
        cnt[(size_t)blockIdx.x * NBINS + i] = h[i];
}

// ---------------- K5b: per-bin scan over chunks (relative); bin totals ------
__global__ __launch_bounds__(NCHUNK) void k_scanchunk(
    const int* __restrict__ cnt, int* __restrict__ ofs,
    int* __restrict__ binTot) {
    __shared__ int sh[NCHUNK];
    int b = blockIdx.x, t = threadIdx.x;
    int v = cnt[(size_t)t * NBINS + b];
    sh[t] = v;
    __syncthreads();
    #pragma unroll
    for (int off = 1; off < NCHUNK; off <<= 1) {
        int u = (t >= off) ? sh[t - off] : 0;
        __syncthreads();
        sh[t] += u;
        __syncthreads();
    }
    ofs[(size_t)t * NBINS + b] = sh[t] - v;   // chunk-exclusive, bin-relative
    if (t == NCHUNK - 1) binTot[b] = sh[t];
}

// ---------------- K5c: scan bin totals -> bin bases (one block) -------------
__global__ __launch_bounds__(NBINS) void k_binscan(
    const int* __restrict__ binTot, int* __restrict__ binBase) {
    __shared__ int sh[NBINS];
    int t = threadIdx.x;
    int v = binTot[t];
    sh[t] = v;
    __syncthreads();
    #pragma unroll
    for (int off = 1; off < NBINS; off <<= 1) {
        int u = (t >= off) ? sh[t - off] : 0;
        __syncthreads();
        sh[t] += u;
        __syncthreads();
    }
    binBase[t] = sh[t] - v;                   // exclusive
    if (t == NBINS - 1) binBase[NBINS] = sh[t];   // == N_EDGES
}

// ---------------- K5d: place records into bin regions (LDS cursors) --------
__global__ __launch_bounds__(256) void k_place(
    const int* __restrict__ ei, const float* __restrict__ P,
    const float* __restrict__ deter, const int* __restrict__ ofs,
    const int* __restrict__ binBase, int2* __restrict__ rec_tmp) {
    __shared__ int cur[NBINS];
    int t = threadIdx.x;
    for (int i = t; i < NBINS; i += 256)
        cur[i] = ofs[(size_t)blockIdx.x * NBINS + i] + binBase[i];
    __syncthreads();
    int e0 = blockIdx.x * EPC;
    for (int i = t; i < EPC; i += 256) {
        int e = e0 + i;
        int src = ei[e];
        int dst = ei[N_EDGES + e];
        int pos = atomicAdd(&cur[dst / NPB], 1);   // LDS atomic
        rec_tmp[pos] = make_int2((dst << 16) | src, pack_pd(P[e], deter[e]));
    }
}

// ---- K5e (fused): per-bin node counts+scan -> row_off; scatter to exact CSR
//      AND compute w[e][h] = fp16(exp(leaky(logit) - 4)) in the same pass.
// A1[dst] is bin-local (~3 KB, L1); A2[src] is an L2/L3-resident 1.6 MB gather;
// the 8 exps/edge hide under the memory ops. The -4 bias cancels in the
// softmax ratio and keeps exp() inside fp16 range.
__global__ __launch_bounds__(256) void k_rebin(
    const int* __restrict__ binBase, const int2* __restrict__ rec_tmp,
    const float* __restrict__ A1, const float* __restrict__ A2,
    const float* __restrict__ cvec, int* __restrict__ row_off,
    int* __restrict__ rec_src, half8* __restrict__ w8) {
    __shared__ int cnt_l[NPB];   // counts -> exclusive global offsets
    __shared__ int cur_l[NPB];   // atomic cursors
    __shared__ float cs[NHEADS];
    int b = blockIdx.x, t = threadIdx.x;
    if (t < NHEADS) cs[t] = cvec[t];
    int s = binBase[b], e = binBase[b + 1];
    int n0 = b * NPB;
    for (int i = t; i < NPB; i += 256) cnt_l[i] = 0;
    __syncthreads();
    for (int i = s + t; i < e; i += 256) {
        int dst = ((unsigned)rec_tmp[i].x) >> 16;
        atomicAdd(&cnt_l[dst - n0], 1);
    }
    __syncthreads();
    if (t == 0) {   // tiny serial scan over 98 entries
        int acc = s;
        for (int i = 0; i < NPB; ++i) {
            int c = cnt_l[i];
            cnt_l[i] = acc;
            cur_l[i] = acc;
            acc += c;
        }
    }
    __syncthreads();
    for (int i = t; i < NPB; i += 256) {
        int n = n0 + i;
        if (n < N_NODES) row_off[n] = cnt_l[i];
    }
    if (b == 0 && t == 0) row_off[N_NODES] = N_EDGES;
    for (int i = s + t; i < e; i += 256) {
        int2 r = rec_tmp[i];
        int dst = ((unsigned)r.x) >> 16;
        int src = r.x & 0xFFFF;
        float2 pd = unpack_pd(r.y);
        int pos = atomicAdd(&cur_l[dst - n0], 1);   // LDS atomic
        rec_src[pos] = src;
        float4 a1lo = *reinterpret_cast<const float4*>(A1 + (size_t)dst * NHEADS);
        float4 a1hi = *reinterpret_cast<const float4*>(A1 + (size_t)dst * NHEADS + 4);
        float4 a2lo = *reinterpret_cast<const float4*>(A2 + (size_t)src * NHEADS);
        float4 a2hi = *reinterpret_cast<const float4*>(A2 + (size_t)src * NHEADS + 4);
        float a1v[8] = {a1lo.x, a1lo.y, a1lo.z, a1lo.w, a1hi.x, a1hi.y, a1hi.z, a1hi.w};
        float a2v[8] = {a2lo.x, a2lo.y, a2lo.z, a2lo.w, a2hi.x, a2hi.y, a2hi.z, a2hi.w};
        half8 o;
        #pragma unroll
        for (int h = 0; h < NHEADS; ++h) {
            float l = a1v[h] + a2v[h] + pd.x * cs[h] + pd.y;
            l = (l >= 0.f) ? l : LEAKY * l;
            o[h] = (_Float16)__expf(l - 4.0f);
        }
        w8[pos] = o;
    }
}

// ---- K6: aggregation: 8-deep gather of w-weighted V rows -------------------
// wave per node; lane d owns dims (2d, 2d+1), head h = d>>3.
// Per edge: broadcast 2B w load + 4B V gather + 2 FMA. 8 independent
// gathers in flight per batch for memory-level parallelism.
__global__ __launch_bounds__(256) void k_agg(
    const int* __restrict__ row_off, const int* __restrict__ rec_src,
    const __half* __restrict__ w, const __half2* __restrict__ Vh2,
    __half* __restrict__ Xh) {
    int n = (blockIdx.x * 256 + threadIdx.x) >> 6;
    int d = threadIdx.x & 63;
    if (n >= N_NODES) return;
    int h = d >> 3;
    int start = row_off[n], end = row_off[n + 1];
    float s = 0.f, accx = 0.f, accy = 0.f;
    int j = start;
    for (; j + 8 <= end; j += 8) {
        int sv[8];
        float wv[8];
        __half2 vv[8];
        #pragma unroll
        for (int k = 0; k < 8; ++k) sv[k] = rec_src[j + k];
        #pragma unroll
        for (int k = 0; k < 8; ++k) wv[k] = __half2float(w[(size_t)(j + k) * NHEADS + h]);
        #pragma unroll
        for (int k = 0; k < 8; ++k) vv[k] = Vh2[(size_t)sv[k] * (DIM / 2) + d];
        #pragma unroll
        for (int k = 0; k < 8; ++k) {
            s += wv[k];
            float2 f = __half22float2(vv[k]);
            accx += wv[k] * f.x;
            accy += wv[k] * f.y;
        }
    }
    for (; j < end; ++j) {
        int src = rec_src[j];
        float wv = __half2float(w[(size_t)j * NHEADS + h]);
        s += wv;
        float2 vf = __half22float2(Vh2[(size_t)src * (DIM / 2) + d]);
        accx += wv * vf.x;
        accy += wv * vf.y;
    }
    float inv = 1.f / (s + 1e-12f);
    __half2 o = __floats2half2_rn(accx * inv, accy * inv);
    *reinterpret_cast<__half2*>(Xh + (size_t)n * 256 + 2 * d) = o;
}

// -- K7: out = Xh(N,256) @ Wch(128,256)^T + bsum, LayerNorm — MFMA -----------
__global__ __launch_bounds__(64) void k_out_mfma(
    const __half* __restrict__ Xh_, const __half* __restrict__ Wch_,
    const float* __restrict__ bsum, const float* __restrict__ ln_g,
    const float* __restrict__ ln_b, float* __restrict__ out) {
    const _Float16* Xh = reinterpret_cast<const _Float16*>(Xh_);
    const _Float16* Wch = reinterpret_cast<const _Float16*>(Wch_);
    int lane = threadIdx.x;          // 0..63
    int m = lane & 15, q = lane >> 4;
    int n0 = blockIdx.x * 32;
    floatx4 z = {0.f, 0.f, 0.f, 0.f};
    floatx4 acc[2][8];
    #pragma unroll
    for (int t = 0; t < 2; ++t)
        #pragma unroll
        for (int j = 0; j < 8; ++j) acc[t][j] = z;
    int r0 = n0 + m;        if (r0 >= N_NODES) r0 = N_NODES - 1;
    int r1 = n0 + 16 + m;   if (r1 >= N_NODES) r1 = N_NODES - 1;
    const _Float16* X0 = Xh + (size_t)r0 * 256 + q * 8;
    const _Float16* X1 = Xh + (size_t)r1 * 256 + q * 8;
    const _Float16* Wb = Wch + (size_t)m * 256 + q * 8;
    #pragma unroll
    for (int ks = 0; ks < 8; ++ks) {
        half8 a0 = *reinterpret_cast<const half8*>(X0 + ks * 32);
        half8 a1 = *reinterpret_cast<const half8*>(X1 + ks * 32);
        #pragma unroll
        for (int j = 0; j < 8; ++j) {
            half8 b = *reinterpret_cast<const half8*>(Wb + (size_t)j * 16 * 256 + ks * 32);
            acc[0][j] = __builtin_amdgcn_mfma_f32_16x16x32_f16(a0, b, acc[0][j], 0, 0, 0);
            acc[1][j] = __builtin_amdgcn_mfma_f32_16x16x32_f16(a1, b, acc[1][j], 0, 0, 0);
        }
    }
    float bsv[8], gv[8], bv[8];
    #pragma unroll
    for (int j = 0; j < 8; ++j) {
        bsv[j] = bsum[j * 16 + m];
        gv[j]  = ln_g[j * 16 + m];
        bv[j]  = ln_b[j * 16 + m];
    }
    #pragma unroll
    for (int t = 0; t < 2; ++t) {
        #pragma unroll
        for (int reg = 0; reg < 4; ++reg) {
            float v[8];
            float s = 0.f, sq = 0.f;
            #pragma unroll
            for (int j = 0; j < 8; ++j) {
                v[j] = acc[t][j][reg] + bsv[j];
                s += v[j];
                sq += v[j] * v[j];
            }
            #pragma unroll
            for (int mk = 1; mk < 16; mk <<= 1) {
                s  += __shfl_xor(s, mk, 64);
                sq += __shfl_xor(sq, mk, 64);
            }
            float mu = s * (1.f / DIM);
            float var = sq * (1.f / DIM) - mu * mu;
            float rs = rsqrtf(var + LN_EPS);
            int n = n0 + t * 16 + q * 4 + reg;
            if (n < N_NODES) {
                #pragma unroll
                for (int j = 0; j < 8; ++j)
                    out[(size_t)n * DIM + j * 16 + m] = (v[j] - mu) * rs * gv[j] + bv[j];
            }
        }
    }
}

// ---------------------------------------------------------------------------
extern "C" void kernel_launch(void* const* d_in, const int* in_sizes, int n_in,
                              void* d_out, int out_size, void* d_ws, size_t ws_size,
                              hipStream_t stream) {
    const float* H      = (const float*)d_in[0];
    const int*   ei     = (const int*)d_in[1];
    const float* P      = (const float*)d_in[2];
    const float* deter  = (const float*)d_in[3];
    const float* W1     = (const float*)d_in[4];
    const float* W2     = (const float*)d_in[5];
    const float* W3     = (const float*)d_in[6];
    const float* W4     = (const float*)d_in[7];
    const float* Wv     = (const float*)d_in[8];
    const float* Wout_w = (const float*)d_in[9];
    const float* Wout_b = (const float*)d_in[10];
    const float* res_w  = (const float*)d_in[11];
    const float* res_b  = (const float*)d_in[12];
    const float* ln_g   = (const float*)d_in[13];
    const float* ln_b   = (const float*)d_in[14];

    float* ws = (float*)d_ws;
    const size_t NH8 = (size_t)N_NODES * NHEADS;   // 400,000

    // ---- workspace layout (subset of the known-good baseline footprint) ----
    __half* Xh  = (__half*)ws;                       // N*256 halves = N*128 words
    float* fbase = ws + (size_t)N_NODES * 128;
    __half* Vh  = (__half*)fbase;                    // N*128 halves = N*64 words
    float* A1   = fbase + (size_t)N_NODES * 64;      // NH8
    float* A2   = A1 + NH8;                          // NH8
    float* cvec = A2 + NH8;                          // 16
    float* bsum = cvec + 16;                         // 128
    __half* Wch  = (__half*)(bsum + 128);            // 128*256 halves = 16384 words
    __half* Wcat = Wch + 128 * 256;                  // 144*128 halves = 9216 words
    int* rec_src = (int*)(Wcat + 144 * 128);         // E ints (3.2 MB)
    int* row_off = rec_src + N_EDGES;                // N+1
    // total < baseline's ~12.2M words (~49 MB)

    // ---- scratch in d_out (25.6 MB), 16B-aligned first:
    //   w8 12.8 MB + rec_tmp 6.4 MB + cnt 0.5 + ofs 0.5 + binTot/Base ~4 KB
    //   = ~20.2 MB. d_out is fully overwritten by k_out_mfma at the end.
    half8* w8    = (half8*)d_out;                    // E * 16 B
    int2* rec_tmp = (int2*)(w8 + N_EDGES);           // E * 8 B
    int* cnt     = (int*)(rec_tmp + N_EDGES);        // NCHUNK*NBINS ints
    int* ofs     = cnt + NCHUNK * NBINS;             // NCHUNK*NBINS ints
    int* binTot  = ofs + NCHUNK * NBINS;             // NBINS
    int* binBase = binTot + NBINS;                   // NBINS+1

    k_weights<<<136, 256, 0, stream>>>(W1, W2, W3, W4, Wout_w, res_w, Wv,
                                       Wout_b, res_b, Wch, Wcat, bsum, cvec);
    k_node_mfma<<<(N_NODES + 31) / 32, 64, 0, stream>>>(H, Wcat, Vh, Xh, A1, A2);
    k_count<<<NCHUNK, 256, 0, stream>>>(ei, cnt);
    k_scanchunk<<<NBINS, NCHUNK, 0, stream>>>(cnt, ofs, binTot);
    k_binscan<<<1, NBINS, 0, stream>>>(binTot, binBase);
    k_place<<<NCHUNK, 256, 0, stream>>>(ei, P, deter, ofs, binBase, rec_tmp);
    k_rebin<<<NBINS, 256, 0, stream>>>(binBase, rec_tmp, A1, A2, cvec,
                                       row_off, rec_src, w8);
    k_agg<<<(N_NODES + 3) / 4, 256, 0, stream>>>(row_off, rec_src,
                                                 (const __half*)w8,
                                                 (const __half2*)Vh, Xh);
    k_out_mfma<<<(N_NODES + 31) / 32, 64, 0, stream>>>(Xh, Wch, bsum, ln_g, ln_b,
                                                       (float*)d_out);
}

// Round 7
// 223.197 us; speedup vs baseline: 2.2767x; 1.0253x over previous
//
#include <hip/hip_runtime.h>
#include <hip/hip_fp16.h>
#include <math.h>

#define N_NODES 50000
#define N_EDGES 800000
#define DIM 128
#define NHEADS 8
#define LN_EPS 1e-5f
#define LEAKY 0.2f
#define NBINS 512
#define NPB 98     // nodes per bin; 512*98 = 50176 >= N_NODES
#define NCHUNK 256 // edge chunks for counting sort
#define EPC 3125   // edges per chunk; 256*3125 = 800000 exactly

typedef _Float16 half8 __attribute__((ext_vector_type(8)));
typedef float floatx4 __attribute__((ext_vector_type(4)));

// ---------------- pack/unpack (P, deter) as half2 in one int ----------------
__device__ __forceinline__ int pack_pd(float p, float dt) {
    __half2 h = __floats2half2_rn(p, dt);
    int r; __builtin_memcpy(&r, &h, 4); return r;
}
__device__ __forceinline__ float2 unpack_pd(int v) {
    __half2 h; __builtin_memcpy(&h, &v, 4);
    return __half22float2(h);   // .x = P, .y = deter
}

// -- K1 (fused): blocks 0..127 -> Wch/Wcat[0:128]/bsum; 128..135 -> attn rows;
//    blocks 136..391 -> per-chunk per-bin histograms (counting sort phase 1).
__global__ __launch_bounds__(256) void k_init(
    const float* __restrict__ W1, const float* __restrict__ W2,
    const float* __restrict__ W3, const float* __restrict__ W4,
    const float* __restrict__ Wout, const float* __restrict__ Wres,
    const float* __restrict__ Wv, const float* __restrict__ bout,
    const float* __restrict__ bres, const int* __restrict__ ei,
    __half* __restrict__ Wch, __half* __restrict__ Wcat,
    float* __restrict__ bsum, float* __restrict__ c,
    int* __restrict__ cnt) {
    __shared__ float red[DIM];
    __shared__ int hh[NBINS];
    int b = blockIdx.x;
    int t = threadIdx.x;
    if (b < 128) {
        int d = b;
        float v = (t < 128) ? Wout[d * 128 + t] : Wres[d * 128 + (t - 128)];
        Wch[(size_t)d * 256 + t] = __float2half_rn(v);
        if (t < 128) Wcat[(size_t)d * DIM + t] = __float2half_rn(Wv[d * 128 + t]);
        if (d == 0 && t < 128) bsum[t] = bout[t] + bres[t];
    } else if (b < 136) {
        int h = b - 128;          // 0..7
        if (t < 128) {
            int k = t;
            float a1 = 0.f, a2 = 0.f;
            for (int d = 0; d < DIM; ++d) {
                float w4 = W4[h * DIM + d];
                a1 += w4 * W1[d * DIM + k];
                a2 += w4 * W2[d * DIM + k];
            }
            Wcat[(size_t)(128 + h) * DIM + k] = __float2half_rn(a1);
            Wcat[(size_t)(136 + h) * DIM + k] = __float2half_rn(a2);
        }
        if (t < 128) red[t] = W4[h * DIM + t] * W3[t];
        __syncthreads();
        if (t == 0) {
            float s = 0.f;
            for (int i = 0; i < DIM; ++i) s += red[i];
            c[h] = s;
        }
    } else {
        int ch = b - 136;         // chunk 0..255
        for (int i = t; i < NBINS; i += 256) hh[i] = 0;
        __syncthreads();
        int e0 = ch * EPC;
        for (int i = t; i < EPC; i += 256) {
            int dst = ei[N_EDGES + e0 + i];
            atomicAdd(&hh[dst / NPB], 1);      // LDS atomic — block-local
        }
        __syncthreads();
        // layout [chunk][bin] so k_place's reload is coalesced
        for (int i = t; i < NBINS; i += 256)
            cnt[(size_t)ch * NBINS + i] = hh[i];
    }
}

// -- K2: MFMA  Y = H @ Wcat^T  (M=N_NODES, N=144, K=128, fp16 in / fp32 acc) -
//   cols 0..127 -> Vh (fp16), cols 128..135 -> A1, 136..143 -> A2 (fp32)
//   side effect: Xh[:,128:256] = fp16(H)  (converted A-fragments)
__global__ __launch_bounds__(64) void k_node_mfma(
    const float* __restrict__ H, const __half* __restrict__ Wcat_,
    __half* __restrict__ Vh, __half* __restrict__ Xh,
    float* __restrict__ A1, float* __restrict__ A2) {
    const _Float16* Wcat = reinterpret_cast<const _Float16*>(Wcat_);
    int lane = threadIdx.x;          // 0..63
    int m = lane & 15, q = lane >> 4;
    int n0 = blockIdx.x * 32;
    floatx4 z = {0.f, 0.f, 0.f, 0.f};
    floatx4 acc[2][9];
    #pragma unroll
    for (int t = 0; t < 2; ++t)
        #pragma unroll
        for (int j = 0; j < 9; ++j) acc[t][j] = z;
    int r0 = n0 + m;        if (r0 >= N_NODES) r0 = N_NODES - 1;
    int r1 = n0 + 16 + m;   if (r1 >= N_NODES) r1 = N_NODES - 1;
    const float* H0 = H + (size_t)r0 * DIM + q * 8;
    const float* H1 = H + (size_t)r1 * DIM + q * 8;
    _Float16* Xw0 = reinterpret_cast<_Float16*>(Xh) + (size_t)r0 * 256 + 128 + q * 8;
    _Float16* Xw1 = reinterpret_cast<_Float16*>(Xh) + (size_t)r1 * 256 + 128 + q * 8;
    const _Float16* Wb = Wcat + (size_t)m * DIM + q * 8;
    #pragma unroll
    for (int ks = 0; ks < 4; ++ks) {
        float4 fa = *reinterpret_cast<const float4*>(H0 + ks * 32);
        float4 fb = *reinterpret_cast<const float4*>(H0 + ks * 32 + 4);
        float4 ga = *reinterpret_cast<const float4*>(H1 + ks * 32);
        float4 gb = *reinterpret_cast<const float4*>(H1 + ks * 32 + 4);
        half8 a0, a1v;
        a0[0] = (_Float16)fa.x; a0[1] = (_Float16)fa.y;
        a0[2] = (_Float16)fa.z; a0[3] = (_Float16)fa.w;
        a0[4] = (_Float16)fb.x; a0[5] = (_Float16)fb.y;
        a0[6] = (_Float16)fb.z; a0[7] = (_Float16)fb.w;
        a1v[0] = (_Float16)ga.x; a1v[1] = (_Float16)ga.y;
        a1v[2] = (_Float16)ga.z; a1v[3] = (_Float16)ga.w;
        a1v[4] = (_Float16)gb.x; a1v[5] = (_Float16)gb.y;
        a1v[6] = (_Float16)gb.z; a1v[7] = (_Float16)gb.w;
        *reinterpret_cast<half8*>(Xw0 + ks * 32) = a0;
        *reinterpret_cast<half8*>(Xw1 + ks * 32) = a1v;
        #pragma unroll
        for (int j = 0; j < 9; ++j) {
            half8 b = *reinterpret_cast<const half8*>(Wb + (size_t)j * 16 * DIM + ks * 32);
            acc[0][j] = __builtin_amdgcn_mfma_f32_16x16x32_f16(a0, b, acc[0][j], 0, 0, 0);
            acc[1][j] = __builtin_amdgcn_mfma_f32_16x16x32_f16(a1v, b, acc[1][j], 0, 0, 0);
        }
    }
    // C/D layout: col = m, row = q*4 + reg (within 16-row tile)
    #pragma unroll
    for (int t = 0; t < 2; ++t) {
        #pragma unroll
        for (int reg = 0; reg < 4; ++reg) {
            int n = n0 + t * 16 + q * 4 + reg;
            if (n < N_NODES) {
                #pragma unroll
                for (int j = 0; j < 8; ++j)
                    Vh[(size_t)n * DIM + j * 16 + m] = __float2half_rn(acc[t][j][reg]);
                float av = acc[t][8][reg];
                if (m < 8) A1[(size_t)n * NHEADS + m] = av;
                else       A2[(size_t)n * NHEADS + (m - 8)] = av;
            }
        }
    }
}

// ---------------- K5b: per-bin scan over chunks (relative); bin totals ------
__global__ __launch_bounds__(NCHUNK) void k_scanchunk(
    const int* __restrict__ cnt, int* __restrict__ ofs,
    int* __restrict__ binTot) {
    __shared__ int sh[NCHUNK];
    int b = blockIdx.x, t = threadIdx.x;
    int v = cnt[(size_t)t * NBINS + b];
    sh[t] = v;
    __syncthreads();
    #pragma unroll
    for (int off = 1; off < NCHUNK; off <<= 1) {
        int u = (t >= off) ? sh[t - off] : 0;
        __syncthreads();
        sh[t] += u;
        __syncthreads();
    }
    ofs[(size_t)t * NBINS + b] = sh[t] - v;   // chunk-exclusive, bin-relative
    if (t == NCHUNK - 1) binTot[b] = sh[t];
}

// -- in-block 512-wide inclusive scan of binTot (2 elems/thread, 256 thr) ----
// On return: sc[i] = sum(binTot[0..i]). ~18 barrier steps, negligible.
__device__ __forceinline__ void scan512(const int* __restrict__ binTot,
                                        int* sc, int t) {
    sc[t] = binTot[t];
    sc[t + 256] = binTot[t + 256];
    __syncthreads();
    #pragma unroll
    for (int off = 1; off < 512; off <<= 1) {
        int a = (t >= off) ? sc[t - off] : 0;
        int b = (t + 256 >= off) ? sc[t + 256 - off] : 0;
        __syncthreads();
        sc[t] += a;
        sc[t + 256] += b;
        __syncthreads();
    }
}

// ---------------- K5d: place records into bin regions (LDS cursors) --------
// Computes bin bases from binTot in-block (replaces the k_binscan kernel).
__global__ __launch_bounds__(256) void k_place(
    const int* __restrict__ ei, const float* __restrict__ P,
    const float* __restrict__ deter, const int* __restrict__ ofs,
    const int* __restrict__ binTot, int2* __restrict__ rec_tmp) {
    __shared__ int sc[NBINS];
    __shared__ int cur[NBINS];
    int t = threadIdx.x;
    scan512(binTot, sc, t);
    // cur[i] = chunk-relative ofs + exclusive bin base
    cur[t]       = ofs[(size_t)blockIdx.x * NBINS + t]       + sc[t]       - binTot[t];
    cur[t + 256] = ofs[(size_t)blockIdx.x * NBINS + t + 256] + sc[t + 256] - binTot[t + 256];
    __syncthreads();
    int e0 = blockIdx.x * EPC;
    for (int i = t; i < EPC; i += 256) {
        int e = e0 + i;
        int src = ei[e];
        int dst = ei[N_EDGES + e];
        int pos = atomicAdd(&cur[dst / NPB], 1);   // LDS atomic
        rec_tmp[pos] = make_int2((dst << 16) | src, pack_pd(P[e], deter[e]));
    }
}

// ---- K5e (fused): per-bin node counts+scan -> row_off; scatter to exact CSR
//      AND compute w[e][h] = fp16(exp(leaky(logit) - 4)) in the same pass.
// Bin bases recomputed in-block from binTot (replaces k_binscan).
__global__ __launch_bounds__(256) void k_rebin(
    const int* __restrict__ binTot, const int2* __restrict__ rec_tmp,
    const float* __restrict__ A1, const float* __restrict__ A2,
    const float* __restrict__ cvec, int* __restrict__ row_off,
    int* __restrict__ rec_src, half8* __restrict__ w8) {
    __shared__ int sc[NBINS];
    __shared__ int cnt_l[NPB];   // counts -> exclusive global offsets
    __shared__ int cur_l[NPB];   // atomic cursors
    __shared__ float cs[NHEADS];
    int b = blockIdx.x, t = threadIdx.x;
    scan512(binTot, sc, t);
    if (t < NHEADS) cs[t] = cvec[t];
    int e = sc[b];               // inclusive sum = end of bin b
    int s = e - binTot[b];       // exclusive = start of bin b
    int n0 = b * NPB;
    for (int i = t; i < NPB; i += 256) cnt_l[i] = 0;
    __syncthreads();
    for (int i = s + t; i < e; i += 256) {
        int dst = ((unsigned)rec_tmp[i].x) >> 16;
        atomicAdd(&cnt_l[dst - n0], 1);
    }
    __syncthreads();
    if (t == 0) {   // tiny serial scan over 98 entries
        int acc = s;
        for (int i = 0; i < NPB; ++i) {
            int c = cnt_l[i];
            cnt_l[i] = acc;
            cur_l[i] = acc;
            acc += c;
        }
    }
    __syncthreads();
    for (int i = t; i < NPB; i += 256) {
        int n = n0 + i;
        if (n < N_NODES) row_off[n] = cnt_l[i];
    }
    if (b == 0 && t == 0) row_off[N_NODES] = N_EDGES;
    for (int i = s + t; i < e; i += 256) {
        int2 r = rec_tmp[i];
        int dst = ((unsigned)r.x) >> 16;
        int src = r.x & 0xFFFF;
        float2 pd = unpack_pd(r.y);
        int pos = atomicAdd(&cur_l[dst - n0], 1);   // LDS atomic
        rec_src[pos] = src;
        float4 a1lo = *reinterpret_cast<const float4*>(A1 + (size_t)dst * NHEADS);
        float4 a1hi = *reinterpret_cast<const float4*>(A1 + (size_t)dst * NHEADS + 4);
        float4 a2lo = *reinterpret_cast<const float4*>(A2 + (size_t)src * NHEADS);
        float4 a2hi = *reinterpret_cast<const float4*>(A2 + (size_t)src * NHEADS + 4);
        float a1v[8] = {a1lo.x, a1lo.y, a1lo.z, a1lo.w, a1hi.x, a1hi.y, a1hi.z, a1hi.w};
        float a2v[8] = {a2lo.x, a2lo.y, a2lo.z, a2lo.w, a2hi.x, a2hi.y, a2hi.z, a2hi.w};
        half8 o;
        #pragma unroll
        for (int h = 0; h < NHEADS; ++h) {
            float l = a1v[h] + a2v[h] + pd.x * cs[h] + pd.y;
            l = (l >= 0.f) ? l : LEAKY * l;
            o[h] = (_Float16)__expf(l - 4.0f);
        }
        w8[pos] = o;
    }
}

// ---- K6: aggregation: 8-deep gather of w-weighted V rows -------------------
// wave per node; lane d owns dims (2d, 2d+1), head h = d>>3.
// Per edge: broadcast 2B w load + 4B V gather + 2 FMA. 8 independent
// gathers in flight per batch for memory-level parallelism.
__global__ __launch_bounds__(256) void k_agg(
    const int* __restrict__ row_off, const int* __restrict__ rec_src,
    const __half* __restrict__ w, const __half2* __restrict__ Vh2,
    __half* __restrict__ Xh) {
    int n = (blockIdx.x * 256 + threadIdx.x) >> 6;
    int d = threadIdx.x & 63;
    if (n >= N_NODES) return;
    int h = d >> 3;
    int start = row_off[n], end = row_off[n + 1];
    float s = 0.f, accx = 0.f, accy = 0.f;
    int j = start;
    for (; j + 8 <= end; j += 8) {
        int sv[8];
        float wv[8];
        __half2 vv[8];
        #pragma unroll
        for (int k = 0; k < 8; ++k) sv[k] = rec_src[j + k];
        #pragma unroll
        for (int k = 0; k < 8; ++k) wv[k] = __half2float(w[(size_t)(j + k) * NHEADS + h]);
        #pragma unroll
        for (int k = 0; k < 8; ++k) vv[k] = Vh2[(size_t)sv[k] * (DIM / 2) + d];
        #pragma unroll
        for (int k = 0; k < 8; ++k) {
            s += wv[k];
            float2 f = __half22float2(vv[k]);
            accx += wv[k] * f.x;
            accy += wv[k] * f.y;
        }
    }
    for (; j < end; ++j) {
        int src = rec_src[j];
        float wv = __half2float(w[(size_t)j * NHEADS + h]);
        s += wv;
        float2 vf = __half22float2(Vh2[(size_t)src * (DIM / 2) + d]);
        accx += wv * vf.x;
        accy += wv * vf.y;
    }
    float inv = 1.f / (s + 1e-12f);
    __half2 o = __floats2half2_rn(accx * inv, accy * inv);
    *reinterpret_cast<__half2*>(Xh + (size_t)n * 256 + 2 * d) = o;
}

// -- K7: out = Xh(N,256) @ Wch(128,256)^T + bsum, LayerNorm — MFMA -----------
__global__ __launch_bounds__(64) void k_out_mfma(
    const __half* __restrict__ Xh_, const __half* __restrict__ Wch_,
    const float* __restrict__ bsum, const float* __restrict__ ln_g,
    const float* __restrict__ ln_b, float* __restrict__ out) {
    const _Float16* Xh = reinterpret_cast<const _Float16*>(Xh_);
    const _Float16* Wch = reinterpret_cast<const _Float16*>(Wch_);
    int lane = threadIdx.x;          // 0..63
    int m = lane & 15, q = lane >> 4;
    int n0 = blockIdx.x * 32;
    floatx4 z = {0.f, 0.f, 0.f, 0.f};
    floatx4 acc[2][8];
    #pragma unroll
    for (int t = 0; t < 2; ++t)
        #pragma unroll
        for (int j = 0; j < 8; ++j) acc[t][j] = z;
    int r0 = n0 + m;        if (r0 >= N_NODES) r0 = N_NODES - 1;
    int r1 = n0 + 16 + m;   if (r1 >= N_NODES) r1 = N_NODES - 1;
    const _Float16* X0 = Xh + (size_t)r0 * 256 + q * 8;
    const _Float16* X1 = Xh + (size_t)r1 * 256 + q * 8;
    const _Float16* Wb = Wch + (size_t)m * 256 + q * 8;
    #pragma unroll
    for (int ks = 0; ks < 8; ++ks) {
        half8 a0 = *reinterpret_cast<const half8*>(X0 + ks * 32);
        half8 a1 = *reinterpret_cast<const half8*>(X1 + ks * 32);
        #pragma unroll
        for (int j = 0; j < 8; ++j) {
            half8 b = *reinterpret_cast<const half8*>(Wb + (size_t)j * 16 * 256 + ks * 32);
            acc[0][j] = __builtin_amdgcn_mfma_f32_16x16x32_f16(a0, b, acc[0][j], 0, 0, 0);
            acc[1][j] = __builtin_amdgcn_mfma_f32_16x16x32_f16(a1, b, acc[1][j], 0, 0, 0);
        }
    }
    float bsv[8], gv[8], bv[8];
    #pragma unroll
    for (int j = 0; j < 8; ++j) {
        bsv[j] = bsum[j * 16 + m];
        gv[j]  = ln_g[j * 16 + m];
        bv[j]  = ln_b[j * 16 + m];
    }
    #pragma unroll
    for (int t = 0; t < 2; ++t) {
        #pragma unroll
        for (int reg = 0; reg < 4; ++reg) {
            float v[8];
            float s = 0.f, sq = 0.f;
            #pragma unroll
            for (int j = 0; j < 8; ++j) {
                v[j] = acc[t][j][reg] + bsv[j];
                s += v[j];
                sq += v[j] * v[j];
            }
            #pragma unroll
            for (int mk = 1; mk < 16; mk <<= 1) {
                s  += __shfl_xor(s, mk, 64);
                sq += __shfl_xor(sq, mk, 64);
            }
            float mu = s * (1.f / DIM);
            float var = sq * (1.f / DIM) - mu * mu;
            float rs = rsqrtf(var + LN_EPS);
            int n = n0 + t * 16 + q * 4 + reg;
            if (n < N_NODES) {
                #pragma unroll
                for (int j = 0; j < 8; ++j)
                    out[(size_t)n * DIM + j * 16 + m] = (v[j] - mu) * rs * gv[j] + bv[j];
            }
        }
    }
}

// ---------------------------------------------------------------------------
extern "C" void kernel_launch(void* const* d_in, const int* in_sizes, int n_in,
                              void* d_out, int out_size, void* d_ws, size_t ws_size,
                              hipStream_t stream) {
    const float* H      = (const float*)d_in[0];
    const int*   ei     = (const int*)d_in[1];
    const float* P      = (const float*)d_in[2];
    const float* deter  = (const float*)d_in[3];
    const float* W1     = (const float*)d_in[4];
    const float* W2     = (const float*)d_in[5];
    const float* W3     = (const float*)d_in[6];
    const float* W4     = (const float*)d_in[7];
    const float* Wv     = (const float*)d_in[8];
    const float* Wout_w = (const float*)d_in[9];
    const float* Wout_b = (const float*)d_in[10];
    const float* res_w  = (const float*)d_in[11];
    const float* res_b  = (const float*)d_in[12];
    const float* ln_g   = (const float*)d_in[13];
    const float* ln_b   = (const float*)d_in[14];

    float* ws = (float*)d_ws;
    const size_t NH8 = (size_t)N_NODES * NHEADS;   // 400,000

    // ---- workspace layout (subset of the known-good baseline footprint) ----
    __half* Xh  = (__half*)ws;                       // N*256 halves = N*128 words
    float* fbase = ws + (size_t)N_NODES * 128;
    __half* Vh  = (__half*)fbase;                    // N*128 halves = N*64 words
    float* A1   = fbase + (size_t)N_NODES * 64;      // NH8
    float* A2   = A1 + NH8;                          // NH8
    float* cvec = A2 + NH8;                          // 16
    float* bsum = cvec + 16;                         // 128
    __half* Wch  = (__half*)(bsum + 128);            // 128*256 halves = 16384 words
    __half* Wcat = Wch + 128 * 256;                  // 144*128 halves = 9216 words
    int* rec_src = (int*)(Wcat + 144 * 128);         // E ints (3.2 MB)
    int* row_off = rec_src + N_EDGES;                // N+1
    // total < baseline's ~12.2M words (~49 MB)

    // ---- scratch in d_out (25.6 MB), 16B-aligned first:
    //   w8 12.8 MB + rec_tmp 6.4 MB + cnt 0.5 + ofs 0.5 + binTot 2 KB
    //   = ~20.2 MB. d_out is fully overwritten by k_out_mfma at the end.
    half8* w8    = (half8*)d_out;                    // E * 16 B
    int2* rec_tmp = (int2*)(w8 + N_EDGES);           // E * 8 B
    int* cnt     = (int*)(rec_tmp + N_EDGES);        // NCHUNK*NBINS ints
    int* ofs     = cnt + NCHUNK * NBINS;             // NCHUNK*NBINS ints
    int* binTot  = ofs + NCHUNK * NBINS;             // NBINS

    k_init<<<136 + NCHUNK, 256, 0, stream>>>(W1, W2, W3, W4, Wout_w, res_w, Wv,
                                             Wout_b, res_b, ei, Wch, Wcat,
                                             bsum, cvec, cnt);
    k_node_mfma<<<(N_NODES + 31) / 32, 64, 0, stream>>>(H, Wcat, Vh, Xh, A1, A2);
    k_scanchunk<<<NBINS, NCHUNK, 0, stream>>>(cnt, ofs, binTot);
    k_place<<<NCHUNK, 256, 0, stream>>>(ei, P, deter, ofs, binTot, rec_tmp);
    k_rebin<<<NBINS, 256, 0, stream>>>(binTot, rec_tmp, A1, A2, cvec,
                                       row_off, rec_src, w8);
    k_agg<<<(N_NODES + 3) / 4, 256, 0, stream>>>(row_off, rec_src,
                                                 (const __half*)w8,
                                                 (const __half2*)Vh, Xh);
    k_out_mfma<<<(N_NODES + 31) / 32, 64, 0, stream>>>(Xh, Wch, bsum, ln_g, ln_b,
                                                       (float*)d_out);
}